// Round 6
// baseline (348.021 us; speedup 1.0000x reference)
//
#include <hip/hip_runtime.h>

typedef unsigned short u16;
typedef __attribute__((ext_vector_type(8))) short short8;
typedef __attribute__((ext_vector_type(4))) float f32x4;

#define MFMA16(a, b, c) __builtin_amdgcn_mfma_f32_16x16x32_bf16((a), (b), (c), 0, 0, 0)
#define WAITV(N) asm volatile("s_waitcnt vmcnt(" #N ")" ::: "memory")
#define BARS() __builtin_amdgcn_s_barrier()
#define MFENCE() asm volatile("" ::: "memory")

__device__ __forceinline__ u16 f2b(float f) {
  unsigned b = __float_as_uint(f);
  b += 0x7FFFu + ((b >> 16) & 1u);
  return (u16)(b >> 16);
}
__device__ __forceinline__ float b2f(u16 u) { return __uint_as_float(((unsigned)u) << 16); }

__device__ __forceinline__ void gload_lds16(const void* g, void* l) {
  __builtin_amdgcn_global_load_lds((const __attribute__((address_space(1))) void*)g,
                                   (__attribute__((address_space(3))) void*)l, 16, 0, 0);
}

// fast exact-enough GELU: erf via Abramowitz-Stegun 7.1.26 (|err|<=1.5e-7)
__device__ __forceinline__ float fast_gelu(float x) {
  const float u = x * 0.70710678118654752f;
  const float au = fabsf(u);
  float d = 1.f + 0.3275911f * au;
  float tt;
  asm("v_rcp_f32 %0, %1" : "=v"(tt) : "v"(d));
  float p = 1.061405429f * tt - 1.453152027f;
  p = p * tt + 1.421413741f;
  p = p * tt - 0.284496736f;
  p = p * tt + 0.254829592f;
  p = p * tt;
  const float e = __expf(-u * u);
  const float erf_au = 1.f - p * e;
  return 0.5f * x * (1.f + copysignf(erf_au, x));
}

// ---------------- merged setup: weight f32->bf16 + bias table expand ----------------
__global__ __launch_bounds__(256) void prep_kernel(
    const float* __restrict__ qkv_w, const float* __restrict__ proj_w,
    const float* __restrict__ fc1_w, const float* __restrict__ fc2_w,
    const float* __restrict__ tbl, const int* __restrict__ ridx,
    u16* __restrict__ wqkv, u16* __restrict__ wproj, u16* __restrict__ wfc1,
    u16* __restrict__ wfc2, float* __restrict__ bfull) {
  int i = blockIdx.x * 256 + threadIdx.x;
  if (i < 196608) {
    wqkv[i] = f2b(qkv_w[i]);
  } else if (i < 262144) {
    wproj[i - 196608] = f2b(proj_w[i - 196608]);
  } else if (i < 524288) {
    wfc1[i - 262144] = f2b(fc1_w[i - 262144]);
  } else if (i < 786432) {
    wfc2[i - 524288] = f2b(fc2_w[i - 524288]);
  } else {
    int j = i - 786432;  // j < 32768
    int hm = j >> 12, nm = j & 4095;
    bfull[j] = tbl[ridx[nm] * 8 + hm];
  }
}

// ---- K1: LN1 + window partition -> Y bf16 [65536][256] + raw shortcut xsb bf16 ----
__global__ __launch_bounds__(256) void ln1_win_kernel(const float* __restrict__ x,
                                                      const float* __restrict__ g,
                                                      const float* __restrict__ b,
                                                      u16* __restrict__ y,
                                                      u16* __restrict__ xsb) {
  __shared__ float red[2][4][64];
  const int bh = blockIdx.x;  // b*64 + h
  const int bb = bh >> 6, h = bh & 63;
  const int w = threadIdx.x & 63, cg = threadIdx.x >> 6;
  const float* xp = x + (size_t)bb * 1048576 + (size_t)h * 64 + w;
  float vals[64];
  float s = 0.f, ss = 0.f;
#pragma unroll
  for (int j = 0; j < 64; ++j) {
    float v = xp[(size_t)(cg * 64 + j) * 4096];
    vals[j] = v;
    s += v;
    ss += v * v;
  }
  red[0][cg][w] = s;
  red[1][cg][w] = ss;
  __syncthreads();
  const float S = red[0][0][w] + red[0][1][w] + red[0][2][w] + red[0][3][w];
  const float Q = red[1][0][w] + red[1][1][w] + red[1][2][w] + red[1][3][w];
  const float m = S * (1.f / 256.f);
  const float rstd = rsqrtf(Q * (1.f / 256.f) - m * m + 1e-5f);
  const int win = bb * 64 + ((h >> 3) << 3) + (w >> 3);
  const int tok = ((h & 7) << 3) + (w & 7);
  const size_t base = (size_t)win * 16384 + tok * 256 + cg * 64;
#pragma unroll
  for (int jj = 0; jj < 8; ++jj) {
    short8 o, raw;
#pragma unroll
    for (int q = 0; q < 8; ++q) {
      const int c64 = jj * 8 + q;
      const int c = cg * 64 + c64;
      raw[q] = (short)f2b(vals[c64]);
      o[q] = (short)f2b((vals[c64] - m) * rstd * g[c] + b[c]);
    }
    *(short8*)&y[base + jj * 8] = o;
    *(short8*)&xsb[base + jj * 8] = raw;
  }
}

// =============== GEMM 256x128 tile: out = A[M x KT] * W[NC x KT]^T + bias ===============
// 512 thr (8 waves 4m x 2n), BK=32, 3 LDS buffers (72KB -> 2 blocks/CU), 2-ahead prefetch,
// counted vmcnt (3 loads/thread/stage -> waits 6/3/0). gload_lds dest linear (tid*16B).
// EPI 0: qkv scatter (+q scale). 2: fc1 + GELU -> bf16. 3: fc2 + bf16 residual -> BCHW f32.
template <int EPI, int KT, int NNT>
__global__ __launch_bounds__(512, 4) void gemm256(const u16* __restrict__ A,
                                                  const u16* __restrict__ W,
                                                  const float* __restrict__ bias,
                                                  u16* __restrict__ outh,
                                                  float* __restrict__ outf,
                                                  const u16* __restrict__ aux) {
  constexpr int NTK = KT >> 5;
  constexpr int NC = NNT * 128;
  __shared__ __align__(16) u16 As[3][8192];  // [256][32]
  __shared__ __align__(16) u16 Bs[3][4096];  // [128][32]
  const int xcd = blockIdx.x & 7, ii = blockIdx.x >> 3;
  const int mt = xcd * 32 + ii / NNT;  // 256 m-tiles, 32 per XCD, nt innermost
  const int nt = ii % NNT;
  const int tid = threadIdx.x;
  const int wv = tid >> 6, lane = tid & 63;
  const int wm = wv >> 1, wn = wv & 1;
  const int rowa = tid >> 2;                                     // 0..127
  const int esl = (((tid & 3) ^ ((tid >> 3) & 3)) << 3);         // swizzled src k elems
  const int lr = lane & 15, lg = lane >> 4;
  const int kq = ((lg ^ ((lr >> 1) & 3)) << 3);                  // swizzled read k elems
  f32x4 acc[4][4];
#pragma unroll
  for (int mi = 0; mi < 4; ++mi)
#pragma unroll
    for (int ni = 0; ni < 4; ++ni) acc[mi][ni] = (f32x4){0.f, 0.f, 0.f, 0.f};
  const u16* Ab = A + (size_t)mt * 256 * KT;
  const u16* Wb = W + (size_t)nt * 128 * KT;

#define STG(BF, T)                                                                      \
  {                                                                                     \
    const int kt_ = (T) << 5;                                                           \
    gload_lds16(Ab + (size_t)rowa * KT + kt_ + esl, &As[BF][tid * 8]);                  \
    gload_lds16(Ab + (size_t)(rowa + 128) * KT + kt_ + esl, &As[BF][tid * 8 + 4096]);   \
    gload_lds16(Wb + (size_t)rowa * KT + kt_ + esl, &Bs[BF][tid * 8]);                  \
  }
#define CMPT(BF)                                                                        \
  {                                                                                     \
    short8 a_[4], b_[4];                                                                \
    _Pragma("unroll") for (int mi = 0; mi < 4; ++mi)                                    \
        a_[mi] = *(const short8*)&As[BF][(wm * 64 + mi * 16 + lr) * 32 + kq];           \
    _Pragma("unroll") for (int ni = 0; ni < 4; ++ni)                                    \
        b_[ni] = *(const short8*)&Bs[BF][(wn * 64 + ni * 16 + lr) * 32 + kq];           \
    _Pragma("unroll") for (int mi = 0; mi < 4; ++mi)                                    \
        _Pragma("unroll") for (int ni = 0; ni < 4; ++ni)                                \
            acc[mi][ni] = MFMA16(a_[mi], b_[ni], acc[mi][ni]);                          \
  }

  STG(0, 0);
  STG(1, 1);
  STG(2, 2);
  int rr = 0;
  for (int t = 0; t < NTK; ++t) {
    if (t + 2 < NTK) {
      WAITV(6);
    } else if (t + 1 < NTK) {
      WAITV(3);
    } else {
      WAITV(0);
    }
    BARS();
    MFENCE();
    CMPT(rr);
    MFENCE();
    BARS();
    if (t + 3 < NTK) STG(rr, t + 3);
    rr = (rr == 2) ? 0 : rr + 1;
  }
#undef STG
#undef CMPT

  const int row0 = mt * 256 + wm * 64 + lg * 4;  // + mi*16 + r
  const int col0 = nt * 128 + wn * 64 + lr;      // + ni*16

  if constexpr (EPI == 0) {
    // scatter into q/k/v [win][head][64][32]; q scaled by 32^-0.5
#pragma unroll
    for (int mi = 0; mi < 4; ++mi)
#pragma unroll
      for (int ni = 0; ni < 4; ++ni) {
        const int col = col0 + ni * 16;
        const int which = col >> 8, cc = col & 255;
        const int head = cc >> 5, hd = cc & 31;
        u16* dst = outh + (size_t)which * 16777216ull;
        const float scl = (which == 0) ? 0.17677669529663689f : 1.0f;
        const float bv = bias[col];
#pragma unroll
        for (int r = 0; r < 4; ++r) {
          const int row = row0 + mi * 16 + r;
          const int win = row >> 6, tk = row & 63;
          dst[(((size_t)(win * 8 + head) << 6) + tk) * 32 + hd] =
              f2b((acc[mi][ni][r] + bv) * scl);
        }
      }
  } else if constexpr (EPI == 2) {
#pragma unroll
    for (int mi = 0; mi < 4; ++mi)
#pragma unroll
      for (int ni = 0; ni < 4; ++ni) {
        const int col = col0 + ni * 16;
        const float bv = bias[col];
#pragma unroll
        for (int r = 0; r < 4; ++r) {
          const int row = row0 + mi * 16 + r;
          outh[(size_t)row * NC + col] = f2b(fast_gelu(acc[mi][ni][r] + bv));
        }
      }
  } else {  // EPI == 3 : fc2 + bf16 residual -> d_out BCHW fp32
#pragma unroll
    for (int mi = 0; mi < 4; ++mi)
#pragma unroll
      for (int ni = 0; ni < 4; ++ni) {
        const int col = col0 + ni * 16;
        const float bv = bias[col];
        const int row = row0 + mi * 16;  // rows row..row+3 are 4 consecutive w
        const int win = row >> 6, tk = row & 63;
        const int bb = win >> 6;
        const int h = (((win >> 3) & 7) << 3) + (tk >> 3);
        const int w = ((win & 7) << 3) + (tk & 7);
        f32x4 v;
#pragma unroll
        for (int r = 0; r < 4; ++r)
          v[r] = acc[mi][ni][r] + bv + b2f(aux[(size_t)(row + r) * 256 + col]);
        *(f32x4*)&outf[(((size_t)bb * 256 + col) * 64 + h) * 64 + w] = v;
      }
  }
}

// ====== proj GEMM 128x256 (full rows) + residual + fused LN2 -> xs2b bf16, h2 bf16 ======
// A = aout [65536][256]; W = proj_w [256][256]; shortcut xsb bf16. xs2b written IN-PLACE
// over aout (each block reads only its own 128 rows, fully, before writing them).
__global__ __launch_bounds__(512, 4) void proj_ln2(const u16* __restrict__ A,
                                                   const u16* __restrict__ W,
                                                   const float* __restrict__ bias,
                                                   const u16* __restrict__ xsb,
                                                   const float* __restrict__ g2,
                                                   const float* __restrict__ b2,
                                                   u16* __restrict__ xs2b,
                                                   u16* __restrict__ h2) {
  __shared__ __align__(16) u16 As[3][4096];  // [128][32]
  __shared__ __align__(16) u16 Bs[3][8192];  // [256][32]
  __shared__ float redS[4][128], redQ[4][128];
  const int mt = blockIdx.x;
  const int tid = threadIdx.x;
  const int wv = tid >> 6, lane = tid & 63;
  const int wm = wv >> 2, wn = wv & 3;  // 2m x 4n
  const int rowa = tid >> 2;
  const int esl = (((tid & 3) ^ ((tid >> 3) & 3)) << 3);
  const int lr = lane & 15, lg = lane >> 4;
  const int kq = ((lg ^ ((lr >> 1) & 3)) << 3);
  f32x4 acc[4][4];
#pragma unroll
  for (int mi = 0; mi < 4; ++mi)
#pragma unroll
    for (int ni = 0; ni < 4; ++ni) acc[mi][ni] = (f32x4){0.f, 0.f, 0.f, 0.f};
  const u16* Ab = A + (size_t)mt * 128 * 256;

#define STG(BF, T)                                                                      \
  {                                                                                     \
    const int kt_ = (T) << 5;                                                           \
    gload_lds16(Ab + (size_t)rowa * 256 + kt_ + esl, &As[BF][tid * 8]);                 \
    gload_lds16(W + (size_t)rowa * 256 + kt_ + esl, &Bs[BF][tid * 8]);                  \
    gload_lds16(W + (size_t)(rowa + 128) * 256 + kt_ + esl, &Bs[BF][tid * 8 + 4096]);   \
  }
#define CMPT(BF)                                                                        \
  {                                                                                     \
    short8 a_[4], b_[4];                                                                \
    _Pragma("unroll") for (int mi = 0; mi < 4; ++mi)                                    \
        a_[mi] = *(const short8*)&As[BF][(wm * 64 + mi * 16 + lr) * 32 + kq];           \
    _Pragma("unroll") for (int ni = 0; ni < 4; ++ni)                                    \
        b_[ni] = *(const short8*)&Bs[BF][(wn * 64 + ni * 16 + lr) * 32 + kq];           \
    _Pragma("unroll") for (int mi = 0; mi < 4; ++mi)                                    \
        _Pragma("unroll") for (int ni = 0; ni < 4; ++ni)                                \
            acc[mi][ni] = MFMA16(a_[mi], b_[ni], acc[mi][ni]);                          \
  }

  STG(0, 0);
  STG(1, 1);
  STG(2, 2);
  int rr = 0;
  for (int t = 0; t < 8; ++t) {
    if (t + 2 < 8) {
      WAITV(6);
    } else if (t + 1 < 8) {
      WAITV(3);
    } else {
      WAITV(0);
    }
    BARS();
    MFENCE();
    CMPT(rr);
    MFENCE();
    BARS();
    if (t + 3 < 8) STG(rr, t + 3);
    rr = (rr == 2) ? 0 : rr + 1;
  }
#undef STG
#undef CMPT

  const int row0 = mt * 128 + wm * 64 + lg * 4;  // + mi*16 + r (global row)
  const int col0 = wn * 64 + lr;                 // + ni*16

  // xs = proj_out + bias + shortcut, accumulated into acc
#pragma unroll
  for (int mi = 0; mi < 4; ++mi)
#pragma unroll
    for (int ni = 0; ni < 4; ++ni) {
      const int col = col0 + ni * 16;
      const float bv = bias[col];
#pragma unroll
      for (int r = 0; r < 4; ++r)
        acc[mi][ni][r] += bv + b2f(xsb[(size_t)(row0 + mi * 16 + r) * 256 + col]);
    }
  // row sums: reduce over ni then over lr lanes; lr==0 writes per-wave partials
#pragma unroll
  for (int mi = 0; mi < 4; ++mi)
#pragma unroll
    for (int r = 0; r < 4; ++r) {
      float s = acc[mi][0][r] + acc[mi][1][r] + acc[mi][2][r] + acc[mi][3][r];
      float q = acc[mi][0][r] * acc[mi][0][r] + acc[mi][1][r] * acc[mi][1][r] +
                acc[mi][2][r] * acc[mi][2][r] + acc[mi][3][r] * acc[mi][3][r];
      s += __shfl_xor(s, 1); q += __shfl_xor(q, 1);
      s += __shfl_xor(s, 2); q += __shfl_xor(q, 2);
      s += __shfl_xor(s, 4); q += __shfl_xor(q, 4);
      s += __shfl_xor(s, 8); q += __shfl_xor(q, 8);
      if (lr == 0) {
        const int rl = wm * 64 + mi * 16 + lg * 4 + r;
        redS[wn][rl] = s;
        redQ[wn][rl] = q;
      }
    }
  __syncthreads();
#pragma unroll
  for (int mi = 0; mi < 4; ++mi)
#pragma unroll
    for (int r = 0; r < 4; ++r) {
      const int rl = wm * 64 + mi * 16 + lg * 4 + r;
      const float S = redS[0][rl] + redS[1][rl] + redS[2][rl] + redS[3][rl];
      const float Q = redQ[0][rl] + redQ[1][rl] + redQ[2][rl] + redQ[3][rl];
      const float m = S * (1.f / 256.f);
      const float rstd = rsqrtf(Q * (1.f / 256.f) - m * m + 1e-5f);
      const size_t row = row0 + mi * 16 + r;
#pragma unroll
      for (int ni = 0; ni < 4; ++ni) {
        const int col = col0 + ni * 16;
        const float v = acc[mi][ni][r];
        xs2b[row * 256 + col] = f2b(v);
        h2[row * 256 + col] = f2b((v - m) * rstd * g2[col] + b2[col]);
      }
    }
}

// ---------------- K3: windowed attention, 1 wave per (window, head) ----------------
__global__ __launch_bounds__(64) void attn_kernel(const u16* __restrict__ qkv,
                                                  const float* __restrict__ biasf,
                                                  u16* __restrict__ aout) {
  __shared__ __align__(16) u16 sqk[5120];  // qs[0,2560) ks[2560,5120); pp overlays
  __shared__ __align__(16) u16 vt[2304];   // v transposed [hd][m], stride 72
  u16* qs = sqk;
  u16* ks = sqk + 2560;
  u16* pp = sqk;
  const int wh = blockIdx.x;
  const int head = wh & 7;
  const int win = wh >> 3;
  const int lane = threadIdx.x;
  const int lr = lane & 15, lg = lane >> 4;
  const u16* qg = qkv + (size_t)wh * 2048;
  const u16* kg = qkv + 16777216ull + (size_t)wh * 2048;
  const u16* vg = qkv + 33554432ull + (size_t)wh * 2048;
#pragma unroll
  for (int i = 0; i < 4; ++i) {
    int ch = i * 64 + lane;
    int r = ch >> 2, qo = (ch & 3) * 8;
    *(short8*)&qs[r * 40 + qo] = *(const short8*)&qg[r * 32 + qo];
    *(short8*)&ks[r * 40 + qo] = *(const short8*)&kg[r * 32 + qo];
  }
  {
    short8 v0 = *(const short8*)&vg[(size_t)lane * 32];
    short8 v1 = *(const short8*)&vg[(size_t)lane * 32 + 8];
    short8 v2 = *(const short8*)&vg[(size_t)lane * 32 + 16];
    short8 v3 = *(const short8*)&vg[(size_t)lane * 32 + 24];
#pragma unroll
    for (int j = 0; j < 8; ++j) {
      vt[j * 72 + lane] = (u16)v0[j];
      vt[(8 + j) * 72 + lane] = (u16)v1[j];
      vt[(16 + j) * 72 + lane] = (u16)v2[j];
      vt[(24 + j) * 72 + lane] = (u16)v3[j];
    }
  }
  __syncthreads();
  f32x4 sf[4][4];
#pragma unroll
  for (int mi = 0; mi < 4; ++mi)
#pragma unroll
    for (int ni = 0; ni < 4; ++ni) sf[mi][ni] = (f32x4){0.f, 0.f, 0.f, 0.f};
  {
    short8 a[4], bq[4];
#pragma unroll
    for (int mi = 0; mi < 4; ++mi) a[mi] = *(const short8*)&qs[(mi * 16 + lr) * 40 + lg * 8];
#pragma unroll
    for (int ni = 0; ni < 4; ++ni) bq[ni] = *(const short8*)&ks[(ni * 16 + lr) * 40 + lg * 8];
#pragma unroll
    for (int mi = 0; mi < 4; ++mi)
#pragma unroll
      for (int ni = 0; ni < 4; ++ni) sf[mi][ni] = MFMA16(a[mi], bq[ni], sf[mi][ni]);
  }
  __syncthreads();  // qs/ks frag reads retired before pp overlay writes
  const float* bh = biasf + (size_t)head * 4096;
#pragma unroll
  for (int mi = 0; mi < 4; ++mi) {
#pragma unroll
    for (int r = 0; r < 4; ++r) {
      const int n = mi * 16 + lg * 4 + r;
      float v0 = sf[mi][0][r] + bh[n * 64 + lr];
      float v1 = sf[mi][1][r] + bh[n * 64 + 16 + lr];
      float v2 = sf[mi][2][r] + bh[n * 64 + 32 + lr];
      float v3 = sf[mi][3][r] + bh[n * 64 + 48 + lr];
      float mx = fmaxf(fmaxf(v0, v1), fmaxf(v2, v3));
      mx = fmaxf(mx, __shfl_xor(mx, 1));
      mx = fmaxf(mx, __shfl_xor(mx, 2));
      mx = fmaxf(mx, __shfl_xor(mx, 4));
      mx = fmaxf(mx, __shfl_xor(mx, 8));
      float e0 = __expf(v0 - mx), e1 = __expf(v1 - mx);
      float e2 = __expf(v2 - mx), e3 = __expf(v3 - mx);
      float sm = e0 + e1 + e2 + e3;
      sm += __shfl_xor(sm, 1);
      sm += __shfl_xor(sm, 2);
      sm += __shfl_xor(sm, 4);
      sm += __shfl_xor(sm, 8);
      const float inv = 1.f / sm;
      pp[n * 72 + lr] = f2b(e0 * inv);
      pp[n * 72 + 16 + lr] = f2b(e1 * inv);
      pp[n * 72 + 32 + lr] = f2b(e2 * inv);
      pp[n * 72 + 48 + lr] = f2b(e3 * inv);
    }
  }
  __syncthreads();
  f32x4 o[4][2];
#pragma unroll
  for (int mi = 0; mi < 4; ++mi)
#pragma unroll
    for (int ni = 0; ni < 2; ++ni) o[mi][ni] = (f32x4){0.f, 0.f, 0.f, 0.f};
#pragma unroll
  for (int kk = 0; kk < 2; ++kk) {
    short8 pa[4], vb[2];
#pragma unroll
    for (int mi = 0; mi < 4; ++mi)
      pa[mi] = *(const short8*)&pp[(mi * 16 + lr) * 72 + kk * 32 + lg * 8];
#pragma unroll
    for (int ni = 0; ni < 2; ++ni)
      vb[ni] = *(const short8*)&vt[(ni * 16 + lr) * 72 + kk * 32 + lg * 8];
#pragma unroll
    for (int mi = 0; mi < 4; ++mi)
#pragma unroll
      for (int ni = 0; ni < 2; ++ni) o[mi][ni] = MFMA16(pa[mi], vb[ni], o[mi][ni]);
  }
  u16* op = aout + (size_t)win * 16384 + head * 32;
#pragma unroll
  for (int mi = 0; mi < 4; ++mi)
#pragma unroll
    for (int ni = 0; ni < 2; ++ni)
#pragma unroll
      for (int r = 0; r < 4; ++r) {
        const int n = mi * 16 + lg * 4 + r;
        op[(size_t)n * 256 + ni * 16 + lr] = f2b(o[mi][ni][r]);
      }
}

extern "C" void kernel_launch(void* const* d_in, const int* in_sizes, int n_in,
                              void* d_out, int out_size, void* d_ws, size_t ws_size,
                              hipStream_t stream) {
  const float* x = (const float*)d_in[0];
  const float* n1g = (const float*)d_in[1];
  const float* n1b = (const float*)d_in[2];
  const float* qkv_w = (const float*)d_in[3];
  const float* qkv_b = (const float*)d_in[4];
  const float* tbl = (const float*)d_in[5];
  const float* proj_w = (const float*)d_in[6];
  const float* proj_b = (const float*)d_in[7];
  const float* n2g = (const float*)d_in[8];
  const float* n2b = (const float*)d_in[9];
  const float* fc1_w = (const float*)d_in[10];
  const float* fc1_b = (const float*)d_in[11];
  const float* fc2_w = (const float*)d_in[12];
  const float* fc2_b = (const float*)d_in[13];
  const int* relidx = (const int*)d_in[14];
  float* outp = (float*)d_out;

  char* w = (char*)d_ws;
  const size_t Mi = 1ull << 20;
  // layout: [0,32): Y -> aout -> xs2b(in-place) ; [32,64): q -> h2 ; [64,96): k ;
  // [96,128): v ; [128,160): xsb ; [64,192): h1 (k,v,xsb dead) ; [192,~194): weights.
  if (ws_size < 237 * Mi) return;
  u16* Y = (u16*)(w + 0);
  u16* qb = (u16*)(w + 32 * Mi);
  u16* aout = (u16*)(w + 0);
  u16* xs2b = (u16*)(w + 0);
  u16* h2 = (u16*)(w + 32 * Mi);
  u16* xsb = (u16*)(w + 128 * Mi);
  u16* h1 = (u16*)(w + 64 * Mi);
  u16* wqkv = (u16*)(w + 192 * Mi);
  u16* wproj = wqkv + 196608;
  u16* wfc1 = wproj + 65536;
  u16* wfc2 = wfc1 + 262144;
  float* bfull = (float*)(w + 192 * Mi + 1572864);

  prep_kernel<<<3200, 256, 0, stream>>>(qkv_w, proj_w, fc1_w, fc2_w, tbl, relidx, wqkv,
                                        wproj, wfc1, wfc2, bfull);
  ln1_win_kernel<<<1024, 256, 0, stream>>>(x, n1g, n1b, Y, xsb);
  gemm256<0, 256, 6><<<1536, 512, 0, stream>>>(Y, wqkv, qkv_b, qb, nullptr, nullptr);
  attn_kernel<<<8192, 64, 0, stream>>>(qb, bfull, aout);
  proj_ln2<<<512, 512, 0, stream>>>(aout, wproj, proj_b, xsb, n2g, n2b, xs2b, h2);
  gemm256<2, 256, 8><<<2048, 512, 0, stream>>>(h2, wfc1, fc1_b, h1, nullptr, nullptr);
  gemm256<3, 1024, 2><<<512, 512, 0, stream>>>(h1, wfc2, fc2_b, nullptr, outp, xs2b);
}

// Round 7
// 338.660 us; speedup vs baseline: 1.0276x; 1.0276x over previous
//
#include <hip/hip_runtime.h>

typedef unsigned short u16;
typedef __attribute__((ext_vector_type(8))) short short8;
typedef __attribute__((ext_vector_type(4))) float f32x4;

#define MFMA16(a, b, c) __builtin_amdgcn_mfma_f32_16x16x32_bf16((a), (b), (c), 0, 0, 0)
#define WAITV(N) asm volatile("s_waitcnt vmcnt(" #N ")" ::: "memory")
#define BARS() __builtin_amdgcn_s_barrier()
#define MFENCE() asm volatile("" ::: "memory")

__device__ __forceinline__ u16 f2b(float f) {
  unsigned b = __float_as_uint(f);
  b += 0x7FFFu + ((b >> 16) & 1u);
  return (u16)(b >> 16);
}
__device__ __forceinline__ float b2f(u16 u) { return __uint_as_float(((unsigned)u) << 16); }

__device__ __forceinline__ void gload_lds16(const void* g, void* l) {
  __builtin_amdgcn_global_load_lds((const __attribute__((address_space(1))) void*)g,
                                   (__attribute__((address_space(3))) void*)l, 16, 0, 0);
}

// fast exact-enough GELU: erf via Abramowitz-Stegun 7.1.26 (|err|<=1.5e-7)
__device__ __forceinline__ float fast_gelu(float x) {
  const float u = x * 0.70710678118654752f;
  const float au = fabsf(u);
  float d = 1.f + 0.3275911f * au;
  float tt;
  asm("v_rcp_f32 %0, %1" : "=v"(tt) : "v"(d));
  float p = 1.061405429f * tt - 1.453152027f;
  p = p * tt + 1.421413741f;
  p = p * tt - 0.284496736f;
  p = p * tt + 0.254829592f;
  p = p * tt;
  const float e = __expf(-u * u);
  const float erf_au = 1.f - p * e;
  return 0.5f * x * (1.f + copysignf(erf_au, x));
}

// ---------------- merged setup: weight f32->bf16 + bias table expand ----------------
__global__ __launch_bounds__(256) void prep_kernel(
    const float* __restrict__ qkv_w, const float* __restrict__ proj_w,
    const float* __restrict__ fc1_w, const float* __restrict__ fc2_w,
    const float* __restrict__ tbl, const int* __restrict__ ridx,
    u16* __restrict__ wqkv, u16* __restrict__ wproj, u16* __restrict__ wfc1,
    u16* __restrict__ wfc2, float* __restrict__ bfull) {
  int i = blockIdx.x * 256 + threadIdx.x;
  if (i < 196608) {
    wqkv[i] = f2b(qkv_w[i]);
  } else if (i < 262144) {
    wproj[i - 196608] = f2b(proj_w[i - 196608]);
  } else if (i < 524288) {
    wfc1[i - 262144] = f2b(fc1_w[i - 262144]);
  } else if (i < 786432) {
    wfc2[i - 524288] = f2b(fc2_w[i - 524288]);
  } else {
    int j = i - 786432;  // j < 32768
    int hm = j >> 12, nm = j & 4095;
    bfull[j] = tbl[ridx[nm] * 8 + hm];
  }
}

// ---- K1: LN1 + window partition -> Y bf16 [65536][256] + raw shortcut xsb bf16 ----
__global__ __launch_bounds__(256) void ln1_win_kernel(const float* __restrict__ x,
                                                      const float* __restrict__ g,
                                                      const float* __restrict__ b,
                                                      u16* __restrict__ y,
                                                      u16* __restrict__ xsb) {
  __shared__ float red[2][4][64];
  const int bh = blockIdx.x;  // b*64 + h
  const int bb = bh >> 6, h = bh & 63;
  const int w = threadIdx.x & 63, cg = threadIdx.x >> 6;
  const float* xp = x + (size_t)bb * 1048576 + (size_t)h * 64 + w;
  float vals[64];
  float s = 0.f, ss = 0.f;
#pragma unroll
  for (int j = 0; j < 64; ++j) {
    float v = xp[(size_t)(cg * 64 + j) * 4096];
    vals[j] = v;
    s += v;
    ss += v * v;
  }
  red[0][cg][w] = s;
  red[1][cg][w] = ss;
  __syncthreads();
  const float S = red[0][0][w] + red[0][1][w] + red[0][2][w] + red[0][3][w];
  const float Q = red[1][0][w] + red[1][1][w] + red[1][2][w] + red[1][3][w];
  const float m = S * (1.f / 256.f);
  const float rstd = rsqrtf(Q * (1.f / 256.f) - m * m + 1e-5f);
  const int win = bb * 64 + ((h >> 3) << 3) + (w >> 3);
  const int tok = ((h & 7) << 3) + (w & 7);
  const size_t base = (size_t)win * 16384 + tok * 256 + cg * 64;
#pragma unroll
  for (int jj = 0; jj < 8; ++jj) {
    short8 o, raw;
#pragma unroll
    for (int q = 0; q < 8; ++q) {
      const int c64 = jj * 8 + q;
      const int c = cg * 64 + c64;
      raw[q] = (short)f2b(vals[c64]);
      o[q] = (short)f2b((vals[c64] - m) * rstd * g[c] + b[c]);
    }
    *(short8*)&y[base + jj * 8] = o;
    *(short8*)&xsb[base + jj * 8] = raw;
  }
}

// ---------------- GEMM: out = A[65536 x KT] * W[NC x KT]^T + bias, bf16 MFMA ----------
// 128x128 tile, BK=32, 3 LDS buffers (48KB -> 3 blocks/CU), 2-tiles-ahead prefetch with
// counted vmcnt (never drained mid-loop). XCD-chunked work remap (A-panel L2-hot).
// EPI 0: qkv -> 3 linear [65536][256] buffers (+q scale), full-line writes.
// EPI 2: fc1 + fast GELU -> bf16. 3: fc2 + bf16 residual -> d_out BCHW fp32.
template <int EPI, int KT, int NNT>
__global__ __launch_bounds__(256, 3) void gemm_bt(const u16* __restrict__ A,
                                                  const u16* __restrict__ W,
                                                  const float* __restrict__ bias,
                                                  u16* __restrict__ outh,
                                                  float* __restrict__ outf,
                                                  const u16* __restrict__ aux) {
  constexpr int NTK = KT >> 5;
  constexpr int NC = NNT * 128;
  __shared__ __align__(16) u16 As[3][4096];
  __shared__ __align__(16) u16 Bs[3][4096];
  const int xcd = blockIdx.x & 7, ii = blockIdx.x >> 3;
  const int mt = xcd * 64 + ii / NNT;  // 512 m-tiles, 64 per XCD, nt innermost
  const int nt = ii % NNT;
  const int tid = threadIdx.x;
  const int wv = tid >> 6, lane = tid & 63;
  const int wr = (wv >> 1) << 6;  // wave row quadrant
  const int wc = (wv & 1) << 6;   // wave col quadrant
  const int lrow4 = lane >> 2;                                  // staged row within 64-group
  const int srcslot = (((lane & 3) ^ ((lane >> 3) & 3)) << 3);  // pre-swizzled k elems
  const int lr = lane & 15, lg = lane >> 4;
  const int kq = ((lg ^ ((lr >> 1) & 3)) << 3);  // swizzled read k-offset (elems)
  f32x4 acc[4][4];
#pragma unroll
  for (int mi = 0; mi < 4; ++mi)
#pragma unroll
    for (int ni = 0; ni < 4; ++ni) acc[mi][ni] = (f32x4){0.f, 0.f, 0.f, 0.f};
  const u16* Ab = A + (size_t)mt * 128 * KT;
  const u16* Wb = W + (size_t)nt * 128 * KT;

#define STG(BF, T)                                                                      \
  {                                                                                     \
    const int kt_ = (T) << 5;                                                           \
    _Pragma("unroll") for (int i_ = 0; i_ < 2; ++i_) {                                  \
      const int row_ = i_ * 64 + wv * 16 + lrow4;                                       \
      const int lo_ = i_ * 2048 + wv * 512;                                             \
      gload_lds16(Ab + (size_t)row_ * KT + kt_ + srcslot, &As[BF][lo_]);                \
      gload_lds16(Wb + (size_t)row_ * KT + kt_ + srcslot, &Bs[BF][lo_]);                \
    }                                                                                   \
  }
#define CMPT(BF)                                                                        \
  {                                                                                     \
    short8 a_[4], b_[4];                                                                \
    _Pragma("unroll") for (int mi = 0; mi < 4; ++mi)                                    \
        a_[mi] = *(const short8*)&As[BF][(wr + mi * 16 + lr) * 32 + kq];                \
    _Pragma("unroll") for (int ni = 0; ni < 4; ++ni)                                    \
        b_[ni] = *(const short8*)&Bs[BF][(wc + ni * 16 + lr) * 32 + kq];                \
    __builtin_amdgcn_s_setprio(1);                                                      \
    _Pragma("unroll") for (int mi = 0; mi < 4; ++mi)                                    \
        _Pragma("unroll") for (int ni = 0; ni < 4; ++ni)                                \
            acc[mi][ni] = MFMA16(a_[mi], b_[ni], acc[mi][ni]);                          \
    __builtin_amdgcn_s_setprio(0);                                                      \
  }

  STG(0, 0);
  STG(1, 1);
  STG(2, 2);
  int rr = 0;
  for (int t = 0; t < NTK; ++t) {
    if (t + 2 < NTK) {
      WAITV(8);  // tile t landed; t+1, t+2 stay in flight
    } else if (t + 1 < NTK) {
      WAITV(4);
    } else {
      WAITV(0);
    }
    BARS();
    MFENCE();
    CMPT(rr);
    MFENCE();
    BARS();  // all waves done reading buffer rr before overwrite
    if (t + 3 < NTK) STG(rr, t + 3);
    rr = (rr == 2) ? 0 : rr + 1;
  }
#undef STG
#undef CMPT

  const int row0 = mt * 128 + wr + lg * 4;  // + mi*16 + r
  const int col0 = nt * 128 + wc + lr;      // + ni*16

  if constexpr (EPI == 0) {
    // q/k/v each [65536][256] (row = win*64+tok, col = head*32+hd); q scaled
#pragma unroll
    for (int mi = 0; mi < 4; ++mi)
#pragma unroll
      for (int ni = 0; ni < 4; ++ni) {
        const int col = col0 + ni * 16;
        const int which = col >> 8, cc = col & 255;
        u16* dst = outh + (size_t)which * 16777216ull;
        const float scl = (which == 0) ? 0.17677669529663689f : 1.0f;
        const float bv = bias[col];
#pragma unroll
        for (int r = 0; r < 4; ++r) {
          const int row = row0 + mi * 16 + r;
          dst[(size_t)row * 256 + cc] = f2b((acc[mi][ni][r] + bv) * scl);
        }
      }
  } else if constexpr (EPI == 2) {
#pragma unroll
    for (int mi = 0; mi < 4; ++mi)
#pragma unroll
      for (int ni = 0; ni < 4; ++ni) {
        const int col = col0 + ni * 16;
        const float bv = bias[col];
#pragma unroll
        for (int r = 0; r < 4; ++r) {
          const int row = row0 + mi * 16 + r;
          outh[(size_t)row * NC + col] = f2b(fast_gelu(acc[mi][ni][r] + bv));
        }
      }
  } else {  // EPI == 3 : fc2 + bf16 residual -> d_out BCHW fp32
#pragma unroll
    for (int mi = 0; mi < 4; ++mi)
#pragma unroll
      for (int ni = 0; ni < 4; ++ni) {
        const int col = col0 + ni * 16;
        const float bv = bias[col];
        const int row = row0 + mi * 16;  // rows row..row+3 are 4 consecutive w
        const int win = row >> 6, tk = row & 63;
        const int bb = win >> 6;
        const int h = (((win >> 3) & 7) << 3) + (tk >> 3);
        const int w = ((win & 7) << 3) + (tk & 7);
        f32x4 v;
#pragma unroll
        for (int r = 0; r < 4; ++r)
          v[r] = acc[mi][ni][r] + bv + b2f(aux[(size_t)(row + r) * 256 + col]);
        *(f32x4*)&outf[(((size_t)bb * 256 + col) * 64 + h) * 64 + w] = v;
      }
  }
}

// ====== proj GEMM 128x256 (full rows) + residual + fused LN2 -> xs2b bf16, h2 bf16 ======
// A = aout [65536][256]; W = proj_w [256][256]; shortcut xsb bf16. xs2b written IN-PLACE
// over aout (each block reads only its own 128 rows, fully, before writing them).
__global__ __launch_bounds__(512, 4) void proj_ln2(const u16* __restrict__ A,
                                                   const u16* __restrict__ W,
                                                   const float* __restrict__ bias,
                                                   const u16* __restrict__ xsb,
                                                   const float* __restrict__ g2,
                                                   const float* __restrict__ b2,
                                                   u16* __restrict__ xs2b,
                                                   u16* __restrict__ h2) {
  __shared__ __align__(16) u16 As[3][4096];  // [128][32]
  __shared__ __align__(16) u16 Bs[3][8192];  // [256][32]
  __shared__ float redS[4][128], redQ[4][128];
  const int mt = blockIdx.x;
  const int tid = threadIdx.x;
  const int wv = tid >> 6, lane = tid & 63;
  const int wm = wv >> 2, wn = wv & 3;  // 2m x 4n
  const int rowa = tid >> 2;
  const int esl = (((tid & 3) ^ ((tid >> 3) & 3)) << 3);
  const int lr = lane & 15, lg = lane >> 4;
  const int kq = ((lg ^ ((lr >> 1) & 3)) << 3);
  f32x4 acc[4][4];
#pragma unroll
  for (int mi = 0; mi < 4; ++mi)
#pragma unroll
    for (int ni = 0; ni < 4; ++ni) acc[mi][ni] = (f32x4){0.f, 0.f, 0.f, 0.f};
  const u16* Ab = A + (size_t)mt * 128 * 256;

#define STG(BF, T)                                                                      \
  {                                                                                     \
    const int kt_ = (T) << 5;                                                           \
    gload_lds16(Ab + (size_t)rowa * 256 + kt_ + esl, &As[BF][tid * 8]);                 \
    gload_lds16(W + (size_t)rowa * 256 + kt_ + esl, &Bs[BF][tid * 8]);                  \
    gload_lds16(W + (size_t)(rowa + 128) * 256 + kt_ + esl, &Bs[BF][tid * 8 + 4096]);   \
  }
#define CMPT(BF)                                                                        \
  {                                                                                     \
    short8 a_[4], b_[4];                                                                \
    _Pragma("unroll") for (int mi = 0; mi < 4; ++mi)                                    \
        a_[mi] = *(const short8*)&As[BF][(wm * 64 + mi * 16 + lr) * 32 + kq];           \
    _Pragma("unroll") for (int ni = 0; ni < 4; ++ni)                                    \
        b_[ni] = *(const short8*)&Bs[BF][(wn * 64 + ni * 16 + lr) * 32 + kq];           \
    __builtin_amdgcn_s_setprio(1);                                                      \
    _Pragma("unroll") for (int mi = 0; mi < 4; ++mi)                                    \
        _Pragma("unroll") for (int ni = 0; ni < 4; ++ni)                                \
            acc[mi][ni] = MFMA16(a_[mi], b_[ni], acc[mi][ni]);                          \
    __builtin_amdgcn_s_setprio(0);                                                      \
  }

  STG(0, 0);
  STG(1, 1);
  STG(2, 2);
  int rr = 0;
  for (int t = 0; t < 8; ++t) {
    if (t + 2 < 8) {
      WAITV(6);
    } else if (t + 1 < 8) {
      WAITV(3);
    } else {
      WAITV(0);
    }
    BARS();
    MFENCE();
    CMPT(rr);
    MFENCE();
    BARS();
    if (t + 3 < 8) STG(rr, t + 3);
    rr = (rr == 2) ? 0 : rr + 1;
  }
#undef STG
#undef CMPT

  const int row0 = mt * 128 + wm * 64 + lg * 4;  // + mi*16 + r (global row)
  const int col0 = wn * 64 + lr;                 // + ni*16

  // xs = proj_out + bias + shortcut, accumulated into acc
#pragma unroll
  for (int mi = 0; mi < 4; ++mi)
#pragma unroll
    for (int ni = 0; ni < 4; ++ni) {
      const int col = col0 + ni * 16;
      const float bv = bias[col];
#pragma unroll
      for (int r = 0; r < 4; ++r)
        acc[mi][ni][r] += bv + b2f(xsb[(size_t)(row0 + mi * 16 + r) * 256 + col]);
    }
  // row sums: reduce over ni then over lr lanes; lr==0 writes per-wave partials
#pragma unroll
  for (int mi = 0; mi < 4; ++mi)
#pragma unroll
    for (int r = 0; r < 4; ++r) {
      float s = acc[mi][0][r] + acc[mi][1][r] + acc[mi][2][r] + acc[mi][3][r];
      float q = acc[mi][0][r] * acc[mi][0][r] + acc[mi][1][r] * acc[mi][1][r] +
                acc[mi][2][r] * acc[mi][2][r] + acc[mi][3][r] * acc[mi][3][r];
      s += __shfl_xor(s, 1); q += __shfl_xor(q, 1);
      s += __shfl_xor(s, 2); q += __shfl_xor(q, 2);
      s += __shfl_xor(s, 4); q += __shfl_xor(q, 4);
      s += __shfl_xor(s, 8); q += __shfl_xor(q, 8);
      if (lr == 0) {
        const int rl = wm * 64 + mi * 16 + lg * 4 + r;
        redS[wn][rl] = s;
        redQ[wn][rl] = q;
      }
    }
  __syncthreads();
#pragma unroll
  for (int mi = 0; mi < 4; ++mi)
#pragma unroll
    for (int r = 0; r < 4; ++r) {
      const int rl = wm * 64 + mi * 16 + lg * 4 + r;
      const float S = redS[0][rl] + redS[1][rl] + redS[2][rl] + redS[3][rl];
      const float Q = redQ[0][rl] + redQ[1][rl] + redQ[2][rl] + redQ[3][rl];
      const float m = S * (1.f / 256.f);
      const float rstd = rsqrtf(Q * (1.f / 256.f) - m * m + 1e-5f);
      const size_t row = row0 + mi * 16 + r;
#pragma unroll
      for (int ni = 0; ni < 4; ++ni) {
        const int col = col0 + ni * 16;
        const float v = acc[mi][ni][r];
        xs2b[row * 256 + col] = f2b(v);
        h2[row * 256 + col] = f2b((v - m) * rstd * g2[col] + b2[col]);
      }
    }
}

// ---------------- K3: windowed attention, 1 wave per (window, head) ----------------
// q/k/v layout: [65536][256], row = win*64+tok, col = head*32+hd
__global__ __launch_bounds__(64) void attn_kernel(const u16* __restrict__ qkv,
                                                  const float* __restrict__ biasf,
                                                  u16* __restrict__ aout) {
  __shared__ __align__(16) u16 sqk[5120];  // qs[0,2560) ks[2560,5120); pp overlays
  __shared__ __align__(16) u16 vt[2304];   // v transposed [hd][m], stride 72
  u16* qs = sqk;
  u16* ks = sqk + 2560;
  u16* pp = sqk;
  const int wh = blockIdx.x;
  const int head = wh & 7;
  const int win = wh >> 3;
  const int lane = threadIdx.x;
  const int lr = lane & 15, lg = lane >> 4;
  const size_t rbase = (size_t)win * 16384 + head * 32;
  const u16* qg = qkv + rbase;
  const u16* kg = qkv + 16777216ull + rbase;
  const u16* vg = qkv + 33554432ull + rbase;
#pragma unroll
  for (int i = 0; i < 4; ++i) {
    int ch = i * 64 + lane;
    int r = ch >> 2, qo = (ch & 3) * 8;
    *(short8*)&qs[r * 40 + qo] = *(const short8*)&qg[(size_t)r * 256 + qo];
    *(short8*)&ks[r * 40 + qo] = *(const short8*)&kg[(size_t)r * 256 + qo];
  }
  {
    short8 v0 = *(const short8*)&vg[(size_t)lane * 256];
    short8 v1 = *(const short8*)&vg[(size_t)lane * 256 + 8];
    short8 v2 = *(const short8*)&vg[(size_t)lane * 256 + 16];
    short8 v3 = *(const short8*)&vg[(size_t)lane * 256 + 24];
#pragma unroll
    for (int j = 0; j < 8; ++j) {
      vt[j * 72 + lane] = (u16)v0[j];
      vt[(8 + j) * 72 + lane] = (u16)v1[j];
      vt[(16 + j) * 72 + lane] = (u16)v2[j];
      vt[(24 + j) * 72 + lane] = (u16)v3[j];
    }
  }
  __syncthreads();
  f32x4 sf[4][4];
#pragma unroll
  for (int mi = 0; mi < 4; ++mi)
#pragma unroll
    for (int ni = 0; ni < 4; ++ni) sf[mi][ni] = (f32x4){0.f, 0.f, 0.f, 0.f};
  {
    short8 a[4], bq[4];
#pragma unroll
    for (int mi = 0; mi < 4; ++mi) a[mi] = *(const short8*)&qs[(mi * 16 + lr) * 40 + lg * 8];
#pragma unroll
    for (int ni = 0; ni < 4; ++ni) bq[ni] = *(const short8*)&ks[(ni * 16 + lr) * 40 + lg * 8];
#pragma unroll
    for (int mi = 0; mi < 4; ++mi)
#pragma unroll
      for (int ni = 0; ni < 4; ++ni) sf[mi][ni] = MFMA16(a[mi], bq[ni], sf[mi][ni]);
  }
  __syncthreads();  // qs/ks frag reads retired before pp overlay writes
  const float* bh = biasf + (size_t)head * 4096;
#pragma unroll
  for (int mi = 0; mi < 4; ++mi) {
#pragma unroll
    for (int r = 0; r < 4; ++r) {
      const int n = mi * 16 + lg * 4 + r;
      float v0 = sf[mi][0][r] + bh[n * 64 + lr];
      float v1 = sf[mi][1][r] + bh[n * 64 + 16 + lr];
      float v2 = sf[mi][2][r] + bh[n * 64 + 32 + lr];
      float v3 = sf[mi][3][r] + bh[n * 64 + 48 + lr];
      float mx = fmaxf(fmaxf(v0, v1), fmaxf(v2, v3));
      mx = fmaxf(mx, __shfl_xor(mx, 1));
      mx = fmaxf(mx, __shfl_xor(mx, 2));
      mx = fmaxf(mx, __shfl_xor(mx, 4));
      mx = fmaxf(mx, __shfl_xor(mx, 8));
      float e0 = __expf(v0 - mx), e1 = __expf(v1 - mx);
      float e2 = __expf(v2 - mx), e3 = __expf(v3 - mx);
      float sm = e0 + e1 + e2 + e3;
      sm += __shfl_xor(sm, 1);
      sm += __shfl_xor(sm, 2);
      sm += __shfl_xor(sm, 4);
      sm += __shfl_xor(sm, 8);
      const float inv = 1.f / sm;
      pp[n * 72 + lr] = f2b(e0 * inv);
      pp[n * 72 + 16 + lr] = f2b(e1 * inv);
      pp[n * 72 + 32 + lr] = f2b(e2 * inv);
      pp[n * 72 + 48 + lr] = f2b(e3 * inv);
    }
  }
  __syncthreads();
  f32x4 o[4][2];
#pragma unroll
  for (int mi = 0; mi < 4; ++mi)
#pragma unroll
    for (int ni = 0; ni < 2; ++ni) o[mi][ni] = (f32x4){0.f, 0.f, 0.f, 0.f};
#pragma unroll
  for (int kk = 0; kk < 2; ++kk) {
    short8 pa[4], vb[2];
#pragma unroll
    for (int mi = 0; mi < 4; ++mi)
      pa[mi] = *(const short8*)&pp[(mi * 16 + lr) * 72 + kk * 32 + lg * 8];
#pragma unroll
    for (int ni = 0; ni < 2; ++ni)
      vb[ni] = *(const short8*)&vt[(ni * 16 + lr) * 72 + kk * 32 + lg * 8];
#pragma unroll
    for (int mi = 0; mi < 4; ++mi)
#pragma unroll
      for (int ni = 0; ni < 2; ++ni) o[mi][ni] = MFMA16(pa[mi], vb[ni], o[mi][ni]);
  }
  u16* op = aout + (size_t)win * 16384 + head * 32;
#pragma unroll
  for (int mi = 0; mi < 4; ++mi)
#pragma unroll
    for (int ni = 0; ni < 2; ++ni)
#pragma unroll
      for (int r = 0; r < 4; ++r) {
        const int n = mi * 16 + lg * 4 + r;
        op[(size_t)n * 256 + ni * 16 + lr] = f2b(o[mi][ni][r]);
      }
}

extern "C" void kernel_launch(void* const* d_in, const int* in_sizes, int n_in,
                              void* d_out, int out_size, void* d_ws, size_t ws_size,
                              hipStream_t stream) {
  const float* x = (const float*)d_in[0];
  const float* n1g = (const float*)d_in[1];
  const float* n1b = (const float*)d_in[2];
  const float* qkv_w = (const float*)d_in[3];
  const float* qkv_b = (const float*)d_in[4];
  const float* tbl = (const float*)d_in[5];
  const float* proj_w = (const float*)d_in[6];
  const float* proj_b = (const float*)d_in[7];
  const float* n2g = (const float*)d_in[8];
  const float* n2b = (const float*)d_in[9];
  const float* fc1_w = (const float*)d_in[10];
  const float* fc1_b = (const float*)d_in[11];
  const float* fc2_w = (const float*)d_in[12];
  const float* fc2_b = (const float*)d_in[13];
  const int* relidx = (const int*)d_in[14];
  float* outp = (float*)d_out;

  char* w = (char*)d_ws;
  const size_t Mi = 1ull << 20;
  // layout: [0,32): Y -> aout -> xs2b(in-place) ; [32,64): q -> h2 ; [64,96): k ;
  // [96,128): v ; [128,160): xsb ; [64,192): h1 (k,v,xsb dead) ; [192,~194): weights.
  if (ws_size < 237 * Mi) return;
  u16* Y = (u16*)(w + 0);
  u16* qb = (u16*)(w + 32 * Mi);
  u16* aout = (u16*)(w + 0);
  u16* xs2b = (u16*)(w + 0);
  u16* h2 = (u16*)(w + 32 * Mi);
  u16* xsb = (u16*)(w + 128 * Mi);
  u16* h1 = (u16*)(w + 64 * Mi);
  u16* wqkv = (u16*)(w + 192 * Mi);
  u16* wproj = wqkv + 196608;
  u16* wfc1 = wproj + 65536;
  u16* wfc2 = wfc1 + 262144;
  float* bfull = (float*)(w + 192 * Mi + 1572864);

  prep_kernel<<<3200, 256, 0, stream>>>(qkv_w, proj_w, fc1_w, fc2_w, tbl, relidx, wqkv,
                                        wproj, wfc1, wfc2, bfull);
  ln1_win_kernel<<<1024, 256, 0, stream>>>(x, n1g, n1b, Y, xsb);
  gemm_bt<0, 256, 6><<<3072, 256, 0, stream>>>(Y, wqkv, qkv_b, qb, nullptr, nullptr);
  attn_kernel<<<8192, 64, 0, stream>>>(qb, bfull, aout);
  proj_ln2<<<512, 512, 0, stream>>>(aout, wproj, proj_b, xsb, n2g, n2b, xs2b, h2);
  gemm_bt<2, 256, 8><<<4096, 256, 0, stream>>>(h2, wfc1, fc1_b, h1, nullptr, nullptr);
  gemm_bt<3, 1024, 2><<<1024, 256, 0, stream>>>(h1, wfc2, fc2_b, nullptr, outp, xs2b);
}

// Round 8
// 326.555 us; speedup vs baseline: 1.0657x; 1.0371x over previous
//
#include <hip/hip_runtime.h>

typedef unsigned short u16;
typedef __attribute__((ext_vector_type(8))) short short8;
typedef __attribute__((ext_vector_type(4))) float f32x4;
typedef __attribute__((ext_vector_type(16))) float f32x16;

#define MFMA32(a, b, c) __builtin_amdgcn_mfma_f32_32x32x16_bf16((a), (b), (c), 0, 0, 0)
#define MFMA16(a, b, c) __builtin_amdgcn_mfma_f32_16x16x32_bf16((a), (b), (c), 0, 0, 0)
#define WAITV(N) asm volatile("s_waitcnt vmcnt(" #N ")" ::: "memory")
#define BARS() __builtin_amdgcn_s_barrier()
#define MFENCE() asm volatile("" ::: "memory")

__device__ __forceinline__ u16 f2b(float f) {
  unsigned b = __float_as_uint(f);
  b += 0x7FFFu + ((b >> 16) & 1u);
  return (u16)(b >> 16);
}
__device__ __forceinline__ float b2f(u16 u) { return __uint_as_float(((unsigned)u) << 16); }

// pack 2 f32 -> 2 bf16 in one u32 (lo = first arg)
__device__ __forceinline__ unsigned cvt2(float lo, float hi) {
  unsigned r;
  asm("v_cvt_pk_bf16_f32 %0, %1, %2" : "=v"(r) : "v"(lo), "v"(hi));
  return r;
}

__device__ __forceinline__ void gload_lds16(const void* g, void* l) {
  __builtin_amdgcn_global_load_lds((const __attribute__((address_space(1))) void*)g,
                                   (__attribute__((address_space(3))) void*)l, 16, 0, 0);
}

// tanh-form GELU via sigmoid: x*sigmoid(2*sqrt(2/pi)*(x+0.044715x^3)); |err|<=3e-4
__device__ __forceinline__ float fast_gelu(float x) {
  const float x2 = x * x;
  const float z = x * (1.5957691216f + 0.0713548162f * x2);
  const float e = __expf(-z);
  float r;
  asm("v_rcp_f32 %0, %1" : "=v"(r) : "v"(1.f + e));
  return x * r;
}

// ---------------- merged setup: weight f32->bf16 + bias table expand ----------------
__global__ __launch_bounds__(256) void prep_kernel(
    const float* __restrict__ qkv_w, const float* __restrict__ proj_w,
    const float* __restrict__ fc1_w, const float* __restrict__ fc2_w,
    const float* __restrict__ tbl, const int* __restrict__ ridx,
    u16* __restrict__ wqkv, u16* __restrict__ wproj, u16* __restrict__ wfc1,
    u16* __restrict__ wfc2, float* __restrict__ bfull) {
  int i = blockIdx.x * 256 + threadIdx.x;
  if (i < 196608) {
    wqkv[i] = f2b(qkv_w[i]);
  } else if (i < 262144) {
    wproj[i - 196608] = f2b(proj_w[i - 196608]);
  } else if (i < 524288) {
    wfc1[i - 262144] = f2b(fc1_w[i - 262144]);
  } else if (i < 786432) {
    wfc2[i - 524288] = f2b(fc2_w[i - 524288]);
  } else {
    int j = i - 786432;  // j < 32768
    int hm = j >> 12, nm = j & 4095;
    bfull[j] = tbl[ridx[nm] * 8 + hm];
  }
}

// ---- K1: LN1 + window partition -> Y bf16 [65536][256] + raw shortcut xsb bf16 ----
__global__ __launch_bounds__(256) void ln1_win_kernel(const float* __restrict__ x,
                                                      const float* __restrict__ g,
                                                      const float* __restrict__ b,
                                                      u16* __restrict__ y,
                                                      u16* __restrict__ xsb) {
  __shared__ float red[2][4][64];
  const int bh = blockIdx.x;  // b*64 + h
  const int bb = bh >> 6, h = bh & 63;
  const int w = threadIdx.x & 63, cg = threadIdx.x >> 6;
  const float* xp = x + (size_t)bb * 1048576 + (size_t)h * 64 + w;
  float vals[64];
  float s = 0.f, ss = 0.f;
#pragma unroll
  for (int j = 0; j < 64; ++j) {
    float v = xp[(size_t)(cg * 64 + j) * 4096];
    vals[j] = v;
    s += v;
    ss += v * v;
  }
  red[0][cg][w] = s;
  red[1][cg][w] = ss;
  __syncthreads();
  const float S = red[0][0][w] + red[0][1][w] + red[0][2][w] + red[0][3][w];
  const float Q = red[1][0][w] + red[1][1][w] + red[1][2][w] + red[1][3][w];
  const float m = S * (1.f / 256.f);
  const float rstd = rsqrtf(Q * (1.f / 256.f) - m * m + 1e-5f);
  const int win = bb * 64 + ((h >> 3) << 3) + (w >> 3);
  const int tok = ((h & 7) << 3) + (w & 7);
  const size_t base = (size_t)win * 16384 + tok * 256 + cg * 64;
#pragma unroll
  for (int jj = 0; jj < 8; ++jj) {
    short8 o, raw;
#pragma unroll
    for (int q = 0; q < 8; ++q) {
      const int c64 = jj * 8 + q;
      const int c = cg * 64 + c64;
      raw[q] = (short)f2b(vals[c64]);
      o[q] = (short)f2b((vals[c64] - m) * rstd * g[c] + b[c]);
    }
    *(short8*)&y[base + jj * 8] = o;
    *(short8*)&xsb[base + jj * 8] = raw;
  }
}

// ---------------- GEMM: out = A[65536 x KT] * W[NC x KT]^T + bias, 32x32x16 MFMA ------
// 128x128 tile, BK=32, 3 LDS buffers (48KB -> 3 blocks/CU), 2-tiles-ahead prefetch with
// counted vmcnt. XCD-chunked work remap. Per wave: 2x2 tiles of 32x32, 8 MFMA/phase.
// LDS swizzle (both-sides involution): row slot s <-> global chunk s ^ ((row>>3)&3).
// EPI 0: qkv -> 3 linear [65536][256] buffers (+q scale).
// EPI 2: fc1 + fast GELU -> bf16. 3: fc2 + bf16 residual -> d_out BCHW fp32.
template <int EPI, int KT, int NNT>
__global__ __launch_bounds__(256, 3) void gemm_bt(const u16* __restrict__ A,
                                                  const u16* __restrict__ W,
                                                  const float* __restrict__ bias,
                                                  u16* __restrict__ outh,
                                                  float* __restrict__ outf,
                                                  const u16* __restrict__ aux) {
  constexpr int NTK = KT >> 5;
  constexpr int NC = NNT * 128;
  __shared__ __align__(16) u16 As[3][4096];
  __shared__ __align__(16) u16 Bs[3][4096];
  const int xcd = blockIdx.x & 7, ii = blockIdx.x >> 3;
  const int mt = xcd * 64 + ii / NNT;  // 512 m-tiles, 64 per XCD, nt innermost
  const int nt = ii % NNT;
  const int tid = threadIdx.x;
  const int wv = tid >> 6, lane = tid & 63;
  const int wr = (wv >> 1) << 6;  // wave row quadrant
  const int wc = (wv & 1) << 6;   // wave col quadrant
  const int srow = tid >> 2;                              // staged row 0..63 (+64)
  const int sslot = (((tid & 3) ^ ((tid >> 5) & 3)) << 3);  // pre-swizzled src k elems
  const int l31 = lane & 31, lh = lane >> 5;
  const int xk = (l31 >> 3) & 3;  // read-side XOR key
  f32x16 acc[2][2];
#pragma unroll
  for (int ti = 0; ti < 2; ++ti)
#pragma unroll
    for (int tj = 0; tj < 2; ++tj)
#pragma unroll
      for (int e = 0; e < 16; ++e) acc[ti][tj][e] = 0.f;
  const u16* Ab = A + (size_t)mt * 128 * KT;
  const u16* Wb = W + (size_t)nt * 128 * KT;

#define STG(BF, T)                                                                      \
  {                                                                                     \
    const int kt_ = (T) << 5;                                                           \
    gload_lds16(Ab + (size_t)srow * KT + kt_ + sslot, &As[BF][tid * 8]);                \
    gload_lds16(Ab + (size_t)(srow + 64) * KT + kt_ + sslot, &As[BF][2048 + tid * 8]);  \
    gload_lds16(Wb + (size_t)srow * KT + kt_ + sslot, &Bs[BF][tid * 8]);                \
    gload_lds16(Wb + (size_t)(srow + 64) * KT + kt_ + sslot, &Bs[BF][2048 + tid * 8]);  \
  }
#define CMPT(BF)                                                                        \
  {                                                                                     \
    short8 a_[2][2], b_[2][2];                                                          \
    _Pragma("unroll") for (int ti = 0; ti < 2; ++ti)                                    \
        _Pragma("unroll") for (int kk = 0; kk < 2; ++kk)                                \
            a_[ti][kk] = *(const short8*)&As[BF][(wr + ti * 32 + l31) * 32 +            \
                                                (((kk * 2 + lh) ^ xk) << 3)];           \
    _Pragma("unroll") for (int tj = 0; tj < 2; ++tj)                                    \
        _Pragma("unroll") for (int kk = 0; kk < 2; ++kk)                                \
            b_[tj][kk] = *(const short8*)&Bs[BF][(wc + tj * 32 + l31) * 32 +            \
                                                (((kk * 2 + lh) ^ xk) << 3)];           \
    _Pragma("unroll") for (int kk = 0; kk < 2; ++kk)                                    \
        _Pragma("unroll") for (int ti = 0; ti < 2; ++ti)                                \
            _Pragma("unroll") for (int tj = 0; tj < 2; ++tj)                            \
                acc[ti][tj] = MFMA32(a_[ti][kk], b_[tj][kk], acc[ti][tj]);              \
  }

  STG(0, 0);
  STG(1, 1);
  STG(2, 2);
  int rr = 0;
  for (int t = 0; t < NTK; ++t) {
    if (t + 2 < NTK) {
      WAITV(8);  // tile t landed; t+1, t+2 stay in flight
    } else if (t + 1 < NTK) {
      WAITV(4);
    } else {
      WAITV(0);
    }
    BARS();
    MFENCE();
    CMPT(rr);
    MFENCE();
    BARS();  // all waves done reading buffer rr before overwrite
    if (t + 3 < NTK) STG(rr, t + 3);
    rr = (rr == 2) ? 0 : rr + 1;
  }
#undef STG
#undef CMPT

  const int row0 = mt * 128 + wr + lh * 4;  // + ti*32 + rg*8 + rq
  const int colL = nt * 128 + wc + l31;     // + tj*32

  if constexpr (EPI == 0) {
    // q/k/v each [65536][256] (row = win*64+tok, col = head*32+hd); q scaled
#pragma unroll
    for (int ti = 0; ti < 2; ++ti)
#pragma unroll
      for (int tj = 0; tj < 2; ++tj) {
        const int col = colL + tj * 32;
        const int which = col >> 8, cc = col & 255;
        u16* dst = outh + (size_t)which * 16777216ull;
        const float scl = (which == 0) ? 0.17677669529663689f : 1.0f;
        const float bv = bias[col];
#pragma unroll
        for (int rg = 0; rg < 4; ++rg) {
          const int rowb = row0 + ti * 32 + rg * 8;
          const unsigned p01 = cvt2((acc[ti][tj][rg * 4 + 0] + bv) * scl,
                                    (acc[ti][tj][rg * 4 + 1] + bv) * scl);
          const unsigned p23 = cvt2((acc[ti][tj][rg * 4 + 2] + bv) * scl,
                                    (acc[ti][tj][rg * 4 + 3] + bv) * scl);
          dst[(size_t)(rowb + 0) * 256 + cc] = (u16)p01;
          dst[(size_t)(rowb + 1) * 256 + cc] = (u16)(p01 >> 16);
          dst[(size_t)(rowb + 2) * 256 + cc] = (u16)p23;
          dst[(size_t)(rowb + 3) * 256 + cc] = (u16)(p23 >> 16);
        }
      }
  } else if constexpr (EPI == 2) {
#pragma unroll
    for (int ti = 0; ti < 2; ++ti)
#pragma unroll
      for (int tj = 0; tj < 2; ++tj) {
        const int col = colL + tj * 32;
        const float bv = bias[col];
#pragma unroll
        for (int rg = 0; rg < 4; ++rg) {
          const int rowb = row0 + ti * 32 + rg * 8;
          const unsigned p01 = cvt2(fast_gelu(acc[ti][tj][rg * 4 + 0] + bv),
                                    fast_gelu(acc[ti][tj][rg * 4 + 1] + bv));
          const unsigned p23 = cvt2(fast_gelu(acc[ti][tj][rg * 4 + 2] + bv),
                                    fast_gelu(acc[ti][tj][rg * 4 + 3] + bv));
          outh[(size_t)(rowb + 0) * NC + col] = (u16)p01;
          outh[(size_t)(rowb + 1) * NC + col] = (u16)(p01 >> 16);
          outh[(size_t)(rowb + 2) * NC + col] = (u16)p23;
          outh[(size_t)(rowb + 3) * NC + col] = (u16)(p23 >> 16);
        }
      }
  } else {  // EPI == 3 : fc2 + bf16 residual -> d_out BCHW fp32
#pragma unroll
    for (int ti = 0; ti < 2; ++ti)
#pragma unroll
      for (int tj = 0; tj < 2; ++tj) {
        const int col = colL + tj * 32;
        const float bv = bias[col];
#pragma unroll
        for (int rg = 0; rg < 4; ++rg) {
          const int rowb = row0 + ti * 32 + rg * 8;  // rows rowb..rowb+3 consecutive w
          const int win = rowb >> 6, tk = rowb & 63;
          const int bb = win >> 6;
          const int h = (((win >> 3) & 7) << 3) + (tk >> 3);
          const int w = ((win & 7) << 3) + (tk & 7);
          f32x4 v;
#pragma unroll
          for (int rq = 0; rq < 4; ++rq)
            v[rq] = acc[ti][tj][rg * 4 + rq] + bv + b2f(aux[(size_t)(rowb + rq) * 256 + col]);
          *(f32x4*)&outf[(((size_t)bb * 256 + col) * 64 + h) * 64 + w] = v;
        }
      }
  }
}

// ====== proj GEMM 128x256 (full rows) + residual + fused LN2 -> xs2b bf16, h2 bf16 ======
__global__ __launch_bounds__(512, 4) void proj_ln2(const u16* __restrict__ A,
                                                   const u16* __restrict__ W,
                                                   const float* __restrict__ bias,
                                                   const u16* __restrict__ xsb,
                                                   const float* __restrict__ g2,
                                                   const float* __restrict__ b2,
                                                   u16* __restrict__ xs2b,
                                                   u16* __restrict__ h2) {
  __shared__ __align__(16) u16 As[3][4096];  // [128][32]
  __shared__ __align__(16) u16 Bs[3][8192];  // [256][32]
  __shared__ float redS[4][128], redQ[4][128];
  const int mt = blockIdx.x;
  const int tid = threadIdx.x;
  const int wv = tid >> 6, lane = tid & 63;
  const int wm = wv >> 2, wn = wv & 3;  // 2m x 4n
  const int rowa = tid >> 2;
  const int esl = (((tid & 3) ^ ((tid >> 3) & 3)) << 3);
  const int lr = lane & 15, lg = lane >> 4;
  const int kq = ((lg ^ ((lr >> 1) & 3)) << 3);
  f32x4 acc[4][4];
#pragma unroll
  for (int mi = 0; mi < 4; ++mi)
#pragma unroll
    for (int ni = 0; ni < 4; ++ni) acc[mi][ni] = (f32x4){0.f, 0.f, 0.f, 0.f};
  const u16* Ab = A + (size_t)mt * 128 * 256;

#define STG(BF, T)                                                                      \
  {                                                                                     \
    const int kt_ = (T) << 5;                                                           \
    gload_lds16(Ab + (size_t)rowa * 256 + kt_ + esl, &As[BF][tid * 8]);                 \
    gload_lds16(W + (size_t)rowa * 256 + kt_ + esl, &Bs[BF][tid * 8]);                  \
    gload_lds16(W + (size_t)(rowa + 128) * 256 + kt_ + esl, &Bs[BF][tid * 8 + 4096]);   \
  }
#define CMPT(BF)                                                                        \
  {                                                                                     \
    short8 a_[4], b_[4];                                                                \
    _Pragma("unroll") for (int mi = 0; mi < 4; ++mi)                                    \
        a_[mi] = *(const short8*)&As[BF][(wm * 64 + mi * 16 + lr) * 32 + kq];           \
    _Pragma("unroll") for (int ni = 0; ni < 4; ++ni)                                    \
        b_[ni] = *(const short8*)&Bs[BF][(wn * 64 + ni * 16 + lr) * 32 + kq];           \
    _Pragma("unroll") for (int mi = 0; mi < 4; ++mi)                                    \
        _Pragma("unroll") for (int ni = 0; ni < 4; ++ni)                                \
            acc[mi][ni] = MFMA16(a_[mi], b_[ni], acc[mi][ni]);                          \
  }

  STG(0, 0);
  STG(1, 1);
  STG(2, 2);
  int rr = 0;
  for (int t = 0; t < 8; ++t) {
    if (t + 2 < 8) {
      WAITV(6);
    } else if (t + 1 < 8) {
      WAITV(3);
    } else {
      WAITV(0);
    }
    BARS();
    MFENCE();
    CMPT(rr);
    MFENCE();
    BARS();
    if (t + 3 < 8) STG(rr, t + 3);
    rr = (rr == 2) ? 0 : rr + 1;
  }
#undef STG
#undef CMPT

  const int row0 = mt * 128 + wm * 64 + lg * 4;  // + mi*16 + r (global row)
  const int col0 = wn * 64 + lr;                 // + ni*16

#pragma unroll
  for (int mi = 0; mi < 4; ++mi)
#pragma unroll
    for (int ni = 0; ni < 4; ++ni) {
      const int col = col0 + ni * 16;
      const float bv = bias[col];
#pragma unroll
      for (int r = 0; r < 4; ++r)
        acc[mi][ni][r] += bv + b2f(xsb[(size_t)(row0 + mi * 16 + r) * 256 + col]);
    }
#pragma unroll
  for (int mi = 0; mi < 4; ++mi)
#pragma unroll
    for (int r = 0; r < 4; ++r) {
      float s = acc[mi][0][r] + acc[mi][1][r] + acc[mi][2][r] + acc[mi][3][r];
      float q = acc[mi][0][r] * acc[mi][0][r] + acc[mi][1][r] * acc[mi][1][r] +
                acc[mi][2][r] * acc[mi][2][r] + acc[mi][3][r] * acc[mi][3][r];
      s += __shfl_xor(s, 1); q += __shfl_xor(q, 1);
      s += __shfl_xor(s, 2); q += __shfl_xor(q, 2);
      s += __shfl_xor(s, 4); q += __shfl_xor(q, 4);
      s += __shfl_xor(s, 8); q += __shfl_xor(q, 8);
      if (lr == 0) {
        const int rl = wm * 64 + mi * 16 + lg * 4 + r;
        redS[wn][rl] = s;
        redQ[wn][rl] = q;
      }
    }
  __syncthreads();
#pragma unroll
  for (int mi = 0; mi < 4; ++mi)
#pragma unroll
    for (int r = 0; r < 4; ++r) {
      const int rl = wm * 64 + mi * 16 + lg * 4 + r;
      const float S = redS[0][rl] + redS[1][rl] + redS[2][rl] + redS[3][rl];
      const float Q = redQ[0][rl] + redQ[1][rl] + redQ[2][rl] + redQ[3][rl];
      const float m = S * (1.f / 256.f);
      const float rstd = rsqrtf(Q * (1.f / 256.f) - m * m + 1e-5f);
      const size_t row = row0 + mi * 16 + r;
#pragma unroll
      for (int ni = 0; ni < 4; ++ni) {
        const int col = col0 + ni * 16;
        const float v = acc[mi][ni][r];
        xs2b[row * 256 + col] = f2b(v);
        h2[row * 256 + col] = f2b((v - m) * rstd * g2[col] + b2[col]);
      }
    }
}

// ---------------- K3: windowed attention, 1 wave per (window, head) ----------------
// q/k/v layout: [65536][256], row = win*64+tok, col = head*32+hd
__global__ __launch_bounds__(64) void attn_kernel(const u16* __restrict__ qkv,
                                                  const float* __restrict__ biasf,
                                                  u16* __restrict__ aout) {
  __shared__ __align__(16) u16 sqk[5120];  // qs[0,2560) ks[2560,5120); pp overlays
  __shared__ __align__(16) u16 vt[2304];   // v transposed [hd][m], stride 72
  u16* qs = sqk;
  u16* ks = sqk + 2560;
  u16* pp = sqk;
  const int wh = blockIdx.x;
  const int head = wh & 7;
  const int win = wh >> 3;
  const int lane = threadIdx.x;
  const int lr = lane & 15, lg = lane >> 4;
  const size_t rbase = (size_t)win * 16384 + head * 32;
  const u16* qg = qkv + rbase;
  const u16* kg = qkv + 16777216ull + rbase;
  const u16* vg = qkv + 33554432ull + rbase;
#pragma unroll
  for (int i = 0; i < 4; ++i) {
    int ch = i * 64 + lane;
    int r = ch >> 2, qo = (ch & 3) * 8;
    *(short8*)&qs[r * 40 + qo] = *(const short8*)&qg[(size_t)r * 256 + qo];
    *(short8*)&ks[r * 40 + qo] = *(const short8*)&kg[(size_t)r * 256 + qo];
  }
  {
    short8 v0 = *(const short8*)&vg[(size_t)lane * 256];
    short8 v1 = *(const short8*)&vg[(size_t)lane * 256 + 8];
    short8 v2 = *(const short8*)&vg[(size_t)lane * 256 + 16];
    short8 v3 = *(const short8*)&vg[(size_t)lane * 256 + 24];
#pragma unroll
    for (int j = 0; j < 8; ++j) {
      vt[j * 72 + lane] = (u16)v0[j];
      vt[(8 + j) * 72 + lane] = (u16)v1[j];
      vt[(16 + j) * 72 + lane] = (u16)v2[j];
      vt[(24 + j) * 72 + lane] = (u16)v3[j];
    }
  }
  __syncthreads();
  f32x4 sf[4][4];
#pragma unroll
  for (int mi = 0; mi < 4; ++mi)
#pragma unroll
    for (int ni = 0; ni < 4; ++ni) sf[mi][ni] = (f32x4){0.f, 0.f, 0.f, 0.f};
  {
    short8 a[4], bq[4];
#pragma unroll
    for (int mi = 0; mi < 4; ++mi) a[mi] = *(const short8*)&qs[(mi * 16 + lr) * 40 + lg * 8];
#pragma unroll
    for (int ni = 0; ni < 4; ++ni) bq[ni] = *(const short8*)&ks[(ni * 16 + lr) * 40 + lg * 8];
#pragma unroll
    for (int mi = 0; mi < 4; ++mi)
#pragma unroll
      for (int ni = 0; ni < 4; ++ni) sf[mi][ni] = MFMA16(a[mi], bq[ni], sf[mi][ni]);
  }
  __syncthreads();  // qs/ks frag reads retired before pp overlay writes
  const float* bh = biasf + (size_t)head * 4096;
#pragma unroll
  for (int mi = 0; mi < 4; ++mi) {
#pragma unroll
    for (int r = 0; r < 4; ++r) {
      const int n = mi * 16 + lg * 4 + r;
      float v0 = sf[mi][0][r] + bh[n * 64 + lr];
      float v1 = sf[mi][1][r] + bh[n * 64 + 16 + lr];
      float v2 = sf[mi][2][r] + bh[n * 64 + 32 + lr];
      float v3 = sf[mi][3][r] + bh[n * 64 + 48 + lr];
      float mx = fmaxf(fmaxf(v0, v1), fmaxf(v2, v3));
      mx = fmaxf(mx, __shfl_xor(mx, 1));
      mx = fmaxf(mx, __shfl_xor(mx, 2));
      mx = fmaxf(mx, __shfl_xor(mx, 4));
      mx = fmaxf(mx, __shfl_xor(mx, 8));
      float e0 = __expf(v0 - mx), e1 = __expf(v1 - mx);
      float e2 = __expf(v2 - mx), e3 = __expf(v3 - mx);
      float sm = e0 + e1 + e2 + e3;
      sm += __shfl_xor(sm, 1);
      sm += __shfl_xor(sm, 2);
      sm += __shfl_xor(sm, 4);
      sm += __shfl_xor(sm, 8);
      const float inv = 1.f / sm;
      pp[n * 72 + lr] = f2b(e0 * inv);
      pp[n * 72 + 16 + lr] = f2b(e1 * inv);
      pp[n * 72 + 32 + lr] = f2b(e2 * inv);
      pp[n * 72 + 48 + lr] = f2b(e3 * inv);
    }
  }
  __syncthreads();
  f32x4 o[4][2];
#pragma unroll
  for (int mi = 0; mi < 4; ++mi)
#pragma unroll
    for (int ni = 0; ni < 2; ++ni) o[mi][ni] = (f32x4){0.f, 0.f, 0.f, 0.f};
#pragma unroll
  for (int kk = 0; kk < 2; ++kk) {
    short8 pa[4], vb[2];
#pragma unroll
    for (int mi = 0; mi < 4; ++mi)
      pa[mi] = *(const short8*)&pp[(mi * 16 + lr) * 72 + kk * 32 + lg * 8];
#pragma unroll
    for (int ni = 0; ni < 2; ++ni)
      vb[ni] = *(const short8*)&vt[(ni * 16 + lr) * 72 + kk * 32 + lg * 8];
#pragma unroll
    for (int mi = 0; mi < 4; ++mi)
#pragma unroll
      for (int ni = 0; ni < 2; ++ni) o[mi][ni] = MFMA16(pa[mi], vb[ni], o[mi][ni]);
  }
  u16* op = aout + (size_t)win * 16384 + head * 32;
#pragma unroll
  for (int mi = 0; mi < 4; ++mi)
#pragma unroll
    for (int ni = 0; ni < 2; ++ni)
#pragma unroll
      for (int r = 0; r < 4; ++r) {
        const int n = mi * 16 + lg * 4 + r;
        op[(size_t)n * 256 + ni * 16 + lr] = f2b(o[mi][ni][r]);
      }
}

extern "C" void kernel_launch(void* const* d_in, const int* in_sizes, int n_in,
                              void* d_out, int out_size, void* d_ws, size_t ws_size,
                              hipStream_t stream) {
  const float* x = (const float*)d_in[0];
  const float* n1g = (const float*)d_in[1];
  const float* n1b = (const float*)d_in[2];
  const float* qkv_w = (const float*)d_in[3];
  const float* qkv_b = (const float*)d_in[4];
  const float* tbl = (const float*)d_in[5];
  const float* proj_w = (const float*)d_in[6];
  const float* proj_b = (const float*)d_in[7];
  const float* n2g = (const float*)d_in[8];
  const float* n2b = (const float*)d_in[9];
  const float* fc1_w = (const float*)d_in[10];
  const float* fc1_b = (const float*)d_in[11];
  const float* fc2_w = (const float*)d_in[12];
  const float* fc2_b = (const float*)d_in[13];
  const int* relidx = (const int*)d_in[14];
  float* outp = (float*)d_out;

  char* w = (char*)d_ws;
  const size_t Mi = 1ull << 20;
  // layout: [0,32): Y -> aout -> xs2b(in-place) ; [32,64): q -> h2 ; [64,96): k ;
  // [96,128): v ; [128,160): xsb ; [64,192): h1 (k,v,xsb dead) ; [192,~194): weights.
  if (ws_size < 237 * Mi) return;
  u16* Y = (u16*)(w + 0);
  u16* qb = (u16*)(w + 32 * Mi);
  u16* aout = (u16*)(w + 0);
  u16* xs2b = (u16*)(w + 0);
  u16* h2 = (u16*)(w + 32 * Mi);
  u16* xsb = (u16*)(w + 128 * Mi);
  u16* h1 = (u16*)(w + 64 * Mi);
  u16* wqkv = (u16*)(w + 192 * Mi);
  u16* wproj = wqkv + 196608;
  u16* wfc1 = wproj + 65536;
  u16* wfc2 = wfc1 + 262144;
  float* bfull = (float*)(w + 192 * Mi + 1572864);

  prep_kernel<<<3200, 256, 0, stream>>>(qkv_w, proj_w, fc1_w, fc2_w, tbl, relidx, wqkv,
                                        wproj, wfc1, wfc2, bfull);
  ln1_win_kernel<<<1024, 256, 0, stream>>>(x, n1g, n1b, Y, xsb);
  gemm_bt<0, 256, 6><<<3072, 256, 0, stream>>>(Y, wqkv, qkv_b, qb, nullptr, nullptr);
  attn_kernel<<<8192, 64, 0, stream>>>(qb, bfull, aout);
  proj_ln2<<<512, 512, 0, stream>>>(aout, wproj, proj_b, xsb, n2g, n2b, xs2b, h2);
  gemm_bt<2, 256, 8><<<4096, 256, 0, stream>>>(h2, wfc1, fc1_b, h1, nullptr, nullptr);
  gemm_bt<3, 1024, 2><<<1024, 256, 0, stream>>>(h1, wfc2, fc2_b, nullptr, outp, xs2b);
}

// Round 9
// 300.910 us; speedup vs baseline: 1.1566x; 1.0852x over previous
//
#include <hip/hip_runtime.h>

typedef unsigned short u16;
typedef __attribute__((ext_vector_type(8))) short short8;
typedef __attribute__((ext_vector_type(4))) float f32x4;
typedef __attribute__((ext_vector_type(16))) float f32x16;

#define MFMA32(a, b, c) __builtin_amdgcn_mfma_f32_32x32x16_bf16((a), (b), (c), 0, 0, 0)
#define MFMA16(a, b, c) __builtin_amdgcn_mfma_f32_16x16x32_bf16((a), (b), (c), 0, 0, 0)
#define WAITV(N) asm volatile("s_waitcnt vmcnt(" #N ")" ::: "memory")
#define BARS() __builtin_amdgcn_s_barrier()
#define MFENCE() asm volatile("" ::: "memory")

__device__ __forceinline__ u16 f2b(float f) {
  unsigned b = __float_as_uint(f);
  b += 0x7FFFu + ((b >> 16) & 1u);
  return (u16)(b >> 16);
}
__device__ __forceinline__ float b2f(u16 u) { return __uint_as_float(((unsigned)u) << 16); }

// pack 2 f32 -> 2 bf16 in one u32 (lo = first arg)
__device__ __forceinline__ unsigned cvt2(float lo, float hi) {
  unsigned r;
  asm("v_cvt_pk_bf16_f32 %0, %1, %2" : "=v"(r) : "v"(lo), "v"(hi));
  return r;
}

__device__ __forceinline__ void gload_lds16(const void* g, void* l) {
  __builtin_amdgcn_global_load_lds((const __attribute__((address_space(1))) void*)g,
                                   (__attribute__((address_space(3))) void*)l, 16, 0, 0);
}

// tanh-form GELU via sigmoid: x*sigmoid(2*sqrt(2/pi)*(x+0.044715x^3)); |err|<=3e-4
__device__ __forceinline__ float fast_gelu(float x) {
  const float x2 = x * x;
  const float z = x * (1.5957691216f + 0.0713548162f * x2);
  const float e = __expf(-z);
  float r;
  asm("v_rcp_f32 %0, %1" : "=v"(r) : "v"(1.f + e));
  return x * r;
}

// ---------------- merged setup: weight f32->bf16 + bias table expand ----------------
__global__ __launch_bounds__(256) void prep_kernel(
    const float* __restrict__ qkv_w, const float* __restrict__ proj_w,
    const float* __restrict__ fc1_w, const float* __restrict__ fc2_w,
    const float* __restrict__ tbl, const int* __restrict__ ridx,
    u16* __restrict__ wqkv, u16* __restrict__ wproj, u16* __restrict__ wfc1,
    u16* __restrict__ wfc2, float* __restrict__ bfull) {
  int i = blockIdx.x * 256 + threadIdx.x;
  if (i < 196608) {
    wqkv[i] = f2b(qkv_w[i]);
  } else if (i < 262144) {
    wproj[i - 196608] = f2b(proj_w[i - 196608]);
  } else if (i < 524288) {
    wfc1[i - 262144] = f2b(fc1_w[i - 262144]);
  } else if (i < 786432) {
    wfc2[i - 524288] = f2b(fc2_w[i - 524288]);
  } else {
    int j = i - 786432;  // j < 32768
    int hm = j >> 12, nm = j & 4095;
    bfull[j] = tbl[ridx[nm] * 8 + hm];
  }
}

// ---- K1: LN1 + window partition -> Y bf16 [65536][256] + raw shortcut xsb bf16 ----
__global__ __launch_bounds__(256) void ln1_win_kernel(const float* __restrict__ x,
                                                      const float* __restrict__ g,
                                                      const float* __restrict__ b,
                                                      u16* __restrict__ y,
                                                      u16* __restrict__ xsb) {
  __shared__ float red[2][4][64];
  const int bh = blockIdx.x;  // b*64 + h
  const int bb = bh >> 6, h = bh & 63;
  const int w = threadIdx.x & 63, cg = threadIdx.x >> 6;
  const float* xp = x + (size_t)bb * 1048576 + (size_t)h * 64 + w;
  float vals[64];
  float s = 0.f, ss = 0.f;
#pragma unroll
  for (int j = 0; j < 64; ++j) {
    float v = xp[(size_t)(cg * 64 + j) * 4096];
    vals[j] = v;
    s += v;
    ss += v * v;
  }
  red[0][cg][w] = s;
  red[1][cg][w] = ss;
  __syncthreads();
  const float S = red[0][0][w] + red[0][1][w] + red[0][2][w] + red[0][3][w];
  const float Q = red[1][0][w] + red[1][1][w] + red[1][2][w] + red[1][3][w];
  const float m = S * (1.f / 256.f);
  const float rstd = rsqrtf(Q * (1.f / 256.f) - m * m + 1e-5f);
  const int win = bb * 64 + ((h >> 3) << 3) + (w >> 3);
  const int tok = ((h & 7) << 3) + (w & 7);
  const size_t base = (size_t)win * 16384 + tok * 256 + cg * 64;
#pragma unroll
  for (int jj = 0; jj < 8; ++jj) {
    short8 o, raw;
#pragma unroll
    for (int q = 0; q < 8; ++q) {
      const int c64 = jj * 8 + q;
      const int c = cg * 64 + c64;
      raw[q] = (short)f2b(vals[c64]);
      o[q] = (short)f2b((vals[c64] - m) * rstd * g[c] + b[c]);
    }
    *(short8*)&y[base + jj * 8] = o;
    *(short8*)&xsb[base + jj * 8] = raw;
  }
}

// ---------------- GEMM: out = A[65536 x KT] * W[NC x KT]^T + bias, 32x32x16 MFMA ------
// 128x128 tile, BK=32, **2 LDS buffers (32KB total)** -> target 5 blocks/CU (m97's
// proven-resident LDS budget), 1-ahead prefetch w/ counted vmcnt; TLP hides latency.
// XCD-chunked work remap. LDS swizzle involution: slot s <-> s ^ ((row>>3)&3).
// EPI 0: qkv -> 3 linear [65536][256] buffers (+q scale).
// EPI 2: fc1 + fast GELU -> bf16. 3: fc2 + bf16 residual -> d_out BCHW fp32.
template <int EPI, int KT, int NNT>
__global__ __launch_bounds__(256, 6) void gemm_bt(const u16* __restrict__ A,
                                                  const u16* __restrict__ W,
                                                  const float* __restrict__ bias,
                                                  u16* __restrict__ outh,
                                                  float* __restrict__ outf,
                                                  const u16* __restrict__ aux) {
  constexpr int NTK = KT >> 5;
  constexpr int NC = NNT * 128;
  __shared__ __align__(16) u16 As[2][4096];
  __shared__ __align__(16) u16 Bs[2][4096];
  const int xcd = blockIdx.x & 7, ii = blockIdx.x >> 3;
  const int mt = xcd * 64 + ii / NNT;  // 512 m-tiles, 64 per XCD, nt innermost
  const int nt = ii % NNT;
  const int tid = threadIdx.x;
  const int wv = tid >> 6, lane = tid & 63;
  const int wr = (wv >> 1) << 6;  // wave row quadrant
  const int wc = (wv & 1) << 6;   // wave col quadrant
  const int srow = tid >> 2;                                // staged row 0..63 (+64)
  const int sslot = (((tid & 3) ^ ((tid >> 5) & 3)) << 3);  // pre-swizzled src k elems
  const int l31 = lane & 31, lh = lane >> 5;
  const int xk = (l31 >> 3) & 3;  // read-side XOR key
  f32x16 acc[2][2];
#pragma unroll
  for (int ti = 0; ti < 2; ++ti)
#pragma unroll
    for (int tj = 0; tj < 2; ++tj)
#pragma unroll
      for (int e = 0; e < 16; ++e) acc[ti][tj][e] = 0.f;
  const u16* Ab = A + (size_t)mt * 128 * KT;
  const u16* Wb = W + (size_t)nt * 128 * KT;

#define STG(BF, T)                                                                      \
  {                                                                                     \
    const int kt_ = (T) << 5;                                                           \
    gload_lds16(Ab + (size_t)srow * KT + kt_ + sslot, &As[BF][tid * 8]);                \
    gload_lds16(Ab + (size_t)(srow + 64) * KT + kt_ + sslot, &As[BF][2048 + tid * 8]);  \
    gload_lds16(Wb + (size_t)srow * KT + kt_ + sslot, &Bs[BF][tid * 8]);                \
    gload_lds16(Wb + (size_t)(srow + 64) * KT + kt_ + sslot, &Bs[BF][2048 + tid * 8]);  \
  }
#define CMPT(BF)                                                                        \
  {                                                                                     \
    short8 a_[2][2], b_[2][2];                                                          \
    _Pragma("unroll") for (int ti = 0; ti < 2; ++ti)                                    \
        _Pragma("unroll") for (int kk = 0; kk < 2; ++kk)                                \
            a_[ti][kk] = *(const short8*)&As[BF][(wr + ti * 32 + l31) * 32 +            \
                                                (((kk * 2 + lh) ^ xk) << 3)];           \
    _Pragma("unroll") for (int tj = 0; tj < 2; ++tj)                                    \
        _Pragma("unroll") for (int kk = 0; kk < 2; ++kk)                                \
            b_[tj][kk] = *(const short8*)&Bs[BF][(wc + tj * 32 + l31) * 32 +            \
                                                (((kk * 2 + lh) ^ xk) << 3)];           \
    _Pragma("unroll") for (int kk = 0; kk < 2; ++kk)                                    \
        _Pragma("unroll") for (int ti = 0; ti < 2; ++ti)                                \
            _Pragma("unroll") for (int tj = 0; tj < 2; ++tj)                            \
                acc[ti][tj] = MFMA32(a_[ti][kk], b_[tj][kk], acc[ti][tj]);              \
  }

  STG(0, 0);
  STG(1, 1);
  int rr = 0;
  for (int t = 0; t < NTK; ++t) {
    if (t + 1 < NTK) {
      WAITV(4);  // tile t landed; t+1's 4 loads stay in flight
    } else {
      WAITV(0);
    }
    BARS();
    MFENCE();
    CMPT(rr);
    MFENCE();
    BARS();  // all waves done reading buffer rr before overwrite
    if (t + 2 < NTK) STG(rr, t + 2);
    rr ^= 1;
  }
#undef STG
#undef CMPT

  const int row0 = mt * 128 + wr + lh * 4;  // + ti*32 + rg*8 + rq
  const int colL = nt * 128 + wc + l31;     // + tj*32

  if constexpr (EPI == 0) {
    // q/k/v each [65536][256] (row = win*64+tok, col = head*32+hd); q scaled
#pragma unroll
    for (int ti = 0; ti < 2; ++ti)
#pragma unroll
      for (int tj = 0; tj < 2; ++tj) {
        const int col = colL + tj * 32;
        const int which = col >> 8, cc = col & 255;
        u16* dst = outh + (size_t)which * 16777216ull;
        const float scl = (which == 0) ? 0.17677669529663689f : 1.0f;
        const float bv = bias[col];
#pragma unroll
        for (int rg = 0; rg < 4; ++rg) {
          const int rowb = row0 + ti * 32 + rg * 8;
          const unsigned p01 = cvt2((acc[ti][tj][rg * 4 + 0] + bv) * scl,
                                    (acc[ti][tj][rg * 4 + 1] + bv) * scl);
          const unsigned p23 = cvt2((acc[ti][tj][rg * 4 + 2] + bv) * scl,
                                    (acc[ti][tj][rg * 4 + 3] + bv) * scl);
          dst[(size_t)(rowb + 0) * 256 + cc] = (u16)p01;
          dst[(size_t)(rowb + 1) * 256 + cc] = (u16)(p01 >> 16);
          dst[(size_t)(rowb + 2) * 256 + cc] = (u16)p23;
          dst[(size_t)(rowb + 3) * 256 + cc] = (u16)(p23 >> 16);
        }
      }
  } else if constexpr (EPI == 2) {
#pragma unroll
    for (int ti = 0; ti < 2; ++ti)
#pragma unroll
      for (int tj = 0; tj < 2; ++tj) {
        const int col = colL + tj * 32;
        const float bv = bias[col];
#pragma unroll
        for (int rg = 0; rg < 4; ++rg) {
          const int rowb = row0 + ti * 32 + rg * 8;
          const unsigned p01 = cvt2(fast_gelu(acc[ti][tj][rg * 4 + 0] + bv),
                                    fast_gelu(acc[ti][tj][rg * 4 + 1] + bv));
          const unsigned p23 = cvt2(fast_gelu(acc[ti][tj][rg * 4 + 2] + bv),
                                    fast_gelu(acc[ti][tj][rg * 4 + 3] + bv));
          outh[(size_t)(rowb + 0) * NC + col] = (u16)p01;
          outh[(size_t)(rowb + 1) * NC + col] = (u16)(p01 >> 16);
          outh[(size_t)(rowb + 2) * NC + col] = (u16)p23;
          outh[(size_t)(rowb + 3) * NC + col] = (u16)(p23 >> 16);
        }
      }
  } else {  // EPI == 3 : fc2 + bf16 residual -> d_out BCHW fp32
#pragma unroll
    for (int ti = 0; ti < 2; ++ti)
#pragma unroll
      for (int tj = 0; tj < 2; ++tj) {
        const int col = colL + tj * 32;
        const float bv = bias[col];
#pragma unroll
        for (int rg = 0; rg < 4; ++rg) {
          const int rowb = row0 + ti * 32 + rg * 8;  // rows rowb..rowb+3 consecutive w
          const int win = rowb >> 6, tk = rowb & 63;
          const int bb = win >> 6;
          const int h = (((win >> 3) & 7) << 3) + (tk >> 3);
          const int w = ((win & 7) << 3) + (tk & 7);
          f32x4 v;
#pragma unroll
          for (int rq = 0; rq < 4; ++rq)
            v[rq] = acc[ti][tj][rg * 4 + rq] + bv + b2f(aux[(size_t)(rowb + rq) * 256 + col]);
          *(f32x4*)&outf[(((size_t)bb * 256 + col) * 64 + h) * 64 + w] = v;
        }
      }
  }
}

// ====== proj GEMM 128x256 (full rows) + residual + fused LN2 -> xs2b bf16, h2 bf16 ======
__global__ __launch_bounds__(512) void proj_ln2(const u16* __restrict__ A,
                                                const u16* __restrict__ W,
                                                const float* __restrict__ bias,
                                                const u16* __restrict__ xsb,
                                                const float* __restrict__ g2,
                                                const float* __restrict__ b2,
                                                u16* __restrict__ xs2b,
                                                u16* __restrict__ h2) {
  __shared__ __align__(16) u16 As[2][4096];  // [128][32]
  __shared__ __align__(16) u16 Bs[2][8192];  // [256][32]
  __shared__ float redS[4][128], redQ[4][128];
  const int mt = blockIdx.x;
  const int tid = threadIdx.x;
  const int wv = tid >> 6, lane = tid & 63;
  const int wm = wv >> 2, wn = wv & 3;  // 2m x 4n
  const int rowa = tid >> 2;
  const int esl = (((tid & 3) ^ ((tid >> 3) & 3)) << 3);
  const int lr = lane & 15, lg = lane >> 4;
  const int kq = ((lg ^ ((lr >> 1) & 3)) << 3);
  f32x4 acc[4][4];
#pragma unroll
  for (int mi = 0; mi < 4; ++mi)
#pragma unroll
    for (int ni = 0; ni < 4; ++ni) acc[mi][ni] = (f32x4){0.f, 0.f, 0.f, 0.f};
  const u16* Ab = A + (size_t)mt * 128 * 256;

#define STG(BF, T)                                                                      \
  {                                                                                     \
    const int kt_ = (T) << 5;                                                           \
    gload_lds16(Ab + (size_t)rowa * 256 + kt_ + esl, &As[BF][tid * 8]);                 \
    gload_lds16(W + (size_t)rowa * 256 + kt_ + esl, &Bs[BF][tid * 8]);                  \
    gload_lds16(W + (size_t)(rowa + 128) * 256 + kt_ + esl, &Bs[BF][tid * 8 + 4096]);   \
  }
#define CMPT(BF)                                                                        \
  {                                                                                     \
    short8 a_[4], b_[4];                                                                \
    _Pragma("unroll") for (int mi = 0; mi < 4; ++mi)                                    \
        a_[mi] = *(const short8*)&As[BF][(wm * 64 + mi * 16 + lr) * 32 + kq];           \
    _Pragma("unroll") for (int ni = 0; ni < 4; ++ni)                                    \
        b_[ni] = *(const short8*)&Bs[BF][(wn * 64 + ni * 16 + lr) * 32 + kq];           \
    _Pragma("unroll") for (int mi = 0; mi < 4; ++mi)                                    \
        _Pragma("unroll") for (int ni = 0; ni < 4; ++ni)                                \
            acc[mi][ni] = MFMA16(a_[mi], b_[ni], acc[mi][ni]);                          \
  }

  STG(0, 0);
  STG(1, 1);
  int rr = 0;
  for (int t = 0; t < 8; ++t) {
    if (t + 1 < 8) {
      WAITV(3);
    } else {
      WAITV(0);
    }
    BARS();
    MFENCE();
    CMPT(rr);
    MFENCE();
    BARS();
    if (t + 2 < 8) STG(rr, t + 2);
    rr ^= 1;
  }
#undef STG
#undef CMPT

  const int row0 = mt * 128 + wm * 64 + lg * 4;  // + mi*16 + r (global row)
  const int col0 = wn * 64 + lr;                 // + ni*16

#pragma unroll
  for (int mi = 0; mi < 4; ++mi)
#pragma unroll
    for (int ni = 0; ni < 4; ++ni) {
      const int col = col0 + ni * 16;
      const float bv = bias[col];
#pragma unroll
      for (int r = 0; r < 4; ++r)
        acc[mi][ni][r] += bv + b2f(xsb[(size_t)(row0 + mi * 16 + r) * 256 + col]);
    }
#pragma unroll
  for (int mi = 0; mi < 4; ++mi)
#pragma unroll
    for (int r = 0; r < 4; ++r) {
      float s = acc[mi][0][r] + acc[mi][1][r] + acc[mi][2][r] + acc[mi][3][r];
      float q = acc[mi][0][r] * acc[mi][0][r] + acc[mi][1][r] * acc[mi][1][r] +
                acc[mi][2][r] * acc[mi][2][r] + acc[mi][3][r] * acc[mi][3][r];
      s += __shfl_xor(s, 1); q += __shfl_xor(q, 1);
      s += __shfl_xor(s, 2); q += __shfl_xor(q, 2);
      s += __shfl_xor(s, 4); q += __shfl_xor(q, 4);
      s += __shfl_xor(s, 8); q += __shfl_xor(q, 8);
      if (lr == 0) {
        const int rl = wm * 64 + mi * 16 + lg * 4 + r;
        redS[wn][rl] = s;
        redQ[wn][rl] = q;
      }
    }
  __syncthreads();
#pragma unroll
  for (int mi = 0; mi < 4; ++mi)
#pragma unroll
    for (int r = 0; r < 4; ++r) {
      const int rl = wm * 64 + mi * 16 + lg * 4 + r;
      const float S = redS[0][rl] + redS[1][rl] + redS[2][rl] + redS[3][rl];
      const float Q = redQ[0][rl] + redQ[1][rl] + redQ[2][rl] + redQ[3][rl];
      const float m = S * (1.f / 256.f);
      const float rstd = rsqrtf(Q * (1.f / 256.f) - m * m + 1e-5f);
      const size_t row = row0 + mi * 16 + r;
#pragma unroll
      for (int ni = 0; ni < 4; ++ni) {
        const int col = col0 + ni * 16;
        const float v = acc[mi][ni][r];
        xs2b[row * 256 + col] = f2b(v);
        h2[row * 256 + col] = f2b((v - m) * rstd * g2[col] + b2[col]);
      }
    }
}

// ---------------- K3: windowed attention, 1 wave per (window, head) ----------------
// q/k/v layout: [65536][256], row = win*64+tok, col = head*32+hd
__global__ __launch_bounds__(64) void attn_kernel(const u16* __restrict__ qkv,
                                                  const float* __restrict__ biasf,
                                                  u16* __restrict__ aout) {
  __shared__ __align__(16) u16 sqk[5120];  // qs[0,2560) ks[2560,5120); pp overlays
  __shared__ __align__(16) u16 vt[2304];   // v transposed [hd][m], stride 72
  u16* qs = sqk;
  u16* ks = sqk + 2560;
  u16* pp = sqk;
  const int wh = blockIdx.x;
  const int head = wh & 7;
  const int win = wh >> 3;
  const int lane = threadIdx.x;
  const int lr = lane & 15, lg = lane >> 4;
  const size_t rbase = (size_t)win * 16384 + head * 32;
  const u16* qg = qkv + rbase;
  const u16* kg = qkv + 16777216ull + rbase;
  const u16* vg = qkv + 33554432ull + rbase;
#pragma unroll
  for (int i = 0; i < 4; ++i) {
    int ch = i * 64 + lane;
    int r = ch >> 2, qo = (ch & 3) * 8;
    *(short8*)&qs[r * 40 + qo] = *(const short8*)&qg[(size_t)r * 256 + qo];
    *(short8*)&ks[r * 40 + qo] = *(const short8*)&kg[(size_t)r * 256 + qo];
  }
  {
    short8 v0 = *(const short8*)&vg[(size_t)lane * 256];
    short8 v1 = *(const short8*)&vg[(size_t)lane * 256 + 8];
    short8 v2 = *(const short8*)&vg[(size_t)lane * 256 + 16];
    short8 v3 = *(const short8*)&vg[(size_t)lane * 256 + 24];
#pragma unroll
    for (int j = 0; j < 8; ++j) {
      vt[j * 72 + lane] = (u16)v0[j];
      vt[(8 + j) * 72 + lane] = (u16)v1[j];
      vt[(16 + j) * 72 + lane] = (u16)v2[j];
      vt[(24 + j) * 72 + lane] = (u16)v3[j];
    }
  }
  __syncthreads();
  f32x4 sf[4][4];
#pragma unroll
  for (int mi = 0; mi < 4; ++mi)
#pragma unroll
    for (int ni = 0; ni < 4; ++ni) sf[mi][ni] = (f32x4){0.f, 0.f, 0.f, 0.f};
  {
    short8 a[4], bq[4];
#pragma unroll
    for (int mi = 0; mi < 4; ++mi) a[mi] = *(const short8*)&qs[(mi * 16 + lr) * 40 + lg * 8];
#pragma unroll
    for (int ni = 0; ni < 4; ++ni) bq[ni] = *(const short8*)&ks[(ni * 16 + lr) * 40 + lg * 8];
#pragma unroll
    for (int mi = 0; mi < 4; ++mi)
#pragma unroll
      for (int ni = 0; ni < 4; ++ni) sf[mi][ni] = MFMA16(a[mi], bq[ni], sf[mi][ni]);
  }
  __syncthreads();  // qs/ks frag reads retired before pp overlay writes
  const float* bh = biasf + (size_t)head * 4096;
#pragma unroll
  for (int mi = 0; mi < 4; ++mi) {
#pragma unroll
    for (int r = 0; r < 4; ++r) {
      const int n = mi * 16 + lg * 4 + r;
      float v0 = sf[mi][0][r] + bh[n * 64 + lr];
      float v1 = sf[mi][1][r] + bh[n * 64 + 16 + lr];
      float v2 = sf[mi][2][r] + bh[n * 64 + 32 + lr];
      float v3 = sf[mi][3][r] + bh[n * 64 + 48 + lr];
      float mx = fmaxf(fmaxf(v0, v1), fmaxf(v2, v3));
      mx = fmaxf(mx, __shfl_xor(mx, 1));
      mx = fmaxf(mx, __shfl_xor(mx, 2));
      mx = fmaxf(mx, __shfl_xor(mx, 4));
      mx = fmaxf(mx, __shfl_xor(mx, 8));
      float e0 = __expf(v0 - mx), e1 = __expf(v1 - mx);
      float e2 = __expf(v2 - mx), e3 = __expf(v3 - mx);
      float sm = e0 + e1 + e2 + e3;
      sm += __shfl_xor(sm, 1);
      sm += __shfl_xor(sm, 2);
      sm += __shfl_xor(sm, 4);
      sm += __shfl_xor(sm, 8);
      const float inv = 1.f / sm;
      pp[n * 72 + lr] = f2b(e0 * inv);
      pp[n * 72 + 16 + lr] = f2b(e1 * inv);
      pp[n * 72 + 32 + lr] = f2b(e2 * inv);
      pp[n * 72 + 48 + lr] = f2b(e3 * inv);
    }
  }
  __syncthreads();
  f32x4 o[4][2];
#pragma unroll
  for (int mi = 0; mi < 4; ++mi)
#pragma unroll
    for (int ni = 0; ni < 2; ++ni) o[mi][ni] = (f32x4){0.f, 0.f, 0.f, 0.f};
#pragma unroll
  for (int kk = 0; kk < 2; ++kk) {
    short8 pa[4], vb[2];
#pragma unroll
    for (int mi = 0; mi < 4; ++mi)
      pa[mi] = *(const short8*)&pp[(mi * 16 + lr) * 72 + kk * 32 + lg * 8];
#pragma unroll
    for (int ni = 0; ni < 2; ++ni)
      vb[ni] = *(const short8*)&vt[(ni * 16 + lr) * 72 + kk * 32 + lg * 8];
#pragma unroll
    for (int mi = 0; mi < 4; ++mi)
#pragma unroll
      for (int ni = 0; ni < 2; ++ni) o[mi][ni] = MFMA16(pa[mi], vb[ni], o[mi][ni]);
  }
  u16* op = aout + (size_t)win * 16384 + head * 32;
#pragma unroll
  for (int mi = 0; mi < 4; ++mi)
#pragma unroll
    for (int ni = 0; ni < 2; ++ni)
#pragma unroll
      for (int r = 0; r < 4; ++r) {
        const int n = mi * 16 + lg * 4 + r;
        op[(size_t)n * 256 + ni * 16 + lr] = f2b(o[mi][ni][r]);
      }
}

extern "C" void kernel_launch(void* const* d_in, const int* in_sizes, int n_in,
                              void* d_out, int out_size, void* d_ws, size_t ws_size,
                              hipStream_t stream) {
  const float* x = (const float*)d_in[0];
  const float* n1g = (const float*)d_in[1];
  const float* n1b = (const float*)d_in[2];
  const float* qkv_w = (const float*)d_in[3];
  const float* qkv_b = (const float*)d_in[4];
  const float* tbl = (const float*)d_in[5];
  const float* proj_w = (const float*)d_in[6];
  const float* proj_b = (const float*)d_in[7];
  const float* n2g = (const float*)d_in[8];
  const float* n2b = (const float*)d_in[9];
  const float* fc1_w = (const float*)d_in[10];
  const float* fc1_b = (const float*)d_in[11];
  const float* fc2_w = (const float*)d_in[12];
  const float* fc2_b = (const float*)d_in[13];
  const int* relidx = (const int*)d_in[14];
  float* outp = (float*)d_out;

  char* w = (char*)d_ws;
  const size_t Mi = 1ull << 20;
  // layout: [0,32): Y -> aout -> xs2b(in-place) ; [32,64): q -> h2 ; [64,96): k ;
  // [96,128): v ; [128,160): xsb ; [64,192): h1 (k,v,xsb dead) ; [192,~194): weights.
  if (ws_size < 237 * Mi) return;
  u16* Y = (u16*)(w + 0);
  u16* qb = (u16*)(w + 32 * Mi);
  u16* aout = (u16*)(w + 0);
  u16* xs2b = (u16*)(w + 0);
  u16* h2 = (u16*)(w + 32 * Mi);
  u16* xsb = (u16*)(w + 128 * Mi);
  u16* h1 = (u16*)(w + 64 * Mi);
  u16* wqkv = (u16*)(w + 192 * Mi);
  u16* wproj = wqkv + 196608;
  u16* wfc1 = wproj + 65536;
  u16* wfc2 = wfc1 + 262144;
  float* bfull = (float*)(w + 192 * Mi + 1572864);

  prep_kernel<<<3200, 256, 0, stream>>>(qkv_w, proj_w, fc1_w, fc2_w, tbl, relidx, wqkv,
                                        wproj, wfc1, wfc2, bfull);
  ln1_win_kernel<<<1024, 256, 0, stream>>>(x, n1g, n1b, Y, xsb);
  gemm_bt<0, 256, 6><<<3072, 256, 0, stream>>>(Y, wqkv, qkv_b, qb, nullptr, nullptr);
  attn_kernel<<<8192, 64, 0, stream>>>(qb, bfull, aout);
  proj_ln2<<<512, 512, 0, stream>>>(aout, wproj, proj_b, xsb, n2g, n2b, xs2b, h2);
  gemm_bt<2, 256, 8><<<4096, 256, 0, stream>>>(h2, wfc1, fc1_b, h1, nullptr, nullptr);
  gemm_bt<3, 1024, 2><<<1024, 256, 0, stream>>>(h1, wfc2, fc2_b, nullptr, outp, xs2b);
}